// Round 7
// baseline (3859.819 us; speedup 1.0000x reference)
//
#include <hip/hip_runtime.h>
#include <stdint.h>

typedef unsigned short u16;
typedef unsigned int u32;
typedef unsigned long long u64;
typedef short short8 __attribute__((ext_vector_type(8)));
typedef unsigned int u32x4 __attribute__((ext_vector_type(4)));
typedef float f32x4 __attribute__((ext_vector_type(4)));
typedef float f32x2 __attribute__((ext_vector_type(2)));

#define T_STEPS 512
#define BATCH 64
#define IDIM 512
#define HDIM 1024
#define TBm (T_STEPS*BATCH)      /* 32768 */
#define N3 (3*HDIM)              /* 3072 */
#define NBLK 128                 /* scan blocks: 4 row-groups x 32 col-blocks */

// ---------------- helpers ----------------
__device__ __forceinline__ float bf2f(u16 s) {
  union { u32 u; float f; } v; v.u = ((u32)s) << 16; return v.f;
}
__device__ __forceinline__ u16 f2b(float f) {
  union { float f; u32 u; } v; v.f = f;
  u32 u = v.u;
  u += 0x7fffu + ((u >> 16) & 1u);   // RNE
  return (u16)(u >> 16);
}
__device__ __forceinline__ float ftanh(float x) {
  x = fminf(20.f, fmaxf(-20.f, x));
  float e = __expf(2.f * x);
  return (e - 1.f) / (e + 1.f);
}
__device__ __forceinline__ float fsigm(float x) {
  x = fminf(30.f, fmaxf(-30.f, x));
  return 1.f / (1.f + __expf(-x));
}

// ---------------- f32 -> (bf16 hi, bf16 lo) split, 4 elems/thread ----------------
__global__ void split_f32(const float* __restrict__ src, u16* __restrict__ hi,
                          u16* __restrict__ lo, int n4) {
  int i = blockIdx.x * blockDim.x + threadIdx.x;
  if (i >= n4) return;
  float4 a = ((const float4*)src)[i];
  u16 h0 = f2b(a.x), h1 = f2b(a.y), h2 = f2b(a.z), h3 = f2b(a.w);
  u16 l0 = f2b(a.x - bf2f(h0)), l1 = f2b(a.y - bf2f(h1));
  u16 l2 = f2b(a.z - bf2f(h2)), l3 = f2b(a.w - bf2f(h3));
  uint2 hv; hv.x = (u32)h0 | ((u32)h1 << 16); hv.y = (u32)h2 | ((u32)h3 << 16);
  uint2 lv; lv.x = (u32)l0 | ((u32)l1 << 16); lv.y = (u32)l2 | ((u32)l3 << 16);
  ((uint2*)hi)[i] = hv;
  ((uint2*)lo)[i] = lv;
}

// ---------------- h0 -> tagged packed h (slot 0, tag 0) ----------------
__global__ void init_h(const float* __restrict__ h0, u32* __restrict__ Hs) {
  int i = blockIdx.x * blockDim.x + threadIdx.x;   // 0..65535
  float v = h0[i];
  u16 hb = f2b(v);
  u16 lb = f2b(v - bf2f(hb));
  Hs[i] = ((u32)hb << 16) | (u32)(lb & 0xFFF8u);   // tag = 0
}

// ---------------- ws-too-small sentinel ----------------
__global__ void ws_small_kernel(float* out, int n, float val) {
  int i = blockIdx.x * blockDim.x + threadIdx.x;
  for (; i < n; i += gridDim.x * blockDim.x) out[i] = val;
}

// ------------- projection GEMM (3-product split): P = Xh@Uh^T + Xh@Ul^T + Xl@Uh^T + b -------------
template<typename PT>
__global__ __launch_bounds__(256) void proj_gemm(const u16* __restrict__ Xh, const u16* __restrict__ Xl,
                                                 const u16* __restrict__ Uh, const u16* __restrict__ Ul,
                                                 const float* __restrict__ bias,
                                                 PT* __restrict__ Pb) {
  __shared__ u16 Ash[4096], Asl[4096], Bsh[4096], Bsl[4096];   // [kc=4][row=128][8]
  const int tid = threadIdx.x;
  const int bm = blockIdx.x, bn = blockIdx.y;
  const int w = tid >> 6, l = tid & 63;
  const int wm = w >> 1, wn = w & 1;
  const int lr = l & 15, kg = l >> 4;

  const int r0t = tid >> 2;           // 0..63
  const int kc = tid & 3;             // k-chunk 0..3
  const size_t ga0 = (size_t)(bm * 128 + r0t) * IDIM + kc * 8;
  const size_t ga1 = ga0 + (size_t)64 * IDIM;
  const size_t gb0 = (size_t)(bn * 128 + r0t) * IDIM + kc * 8;
  const size_t gb1 = gb0 + (size_t)64 * IDIM;
  const int la0 = (kc * 128 + r0t) * 8;
  const int la1 = la0 + 64 * 8;

  uint4 rah0 = *(const uint4*)(Xh + ga0);
  uint4 rah1 = *(const uint4*)(Xh + ga1);
  uint4 ral0 = *(const uint4*)(Xl + ga0);
  uint4 ral1 = *(const uint4*)(Xl + ga1);
  uint4 rbh0 = *(const uint4*)(Uh + gb0);
  uint4 rbh1 = *(const uint4*)(Uh + gb1);
  uint4 rbl0 = *(const uint4*)(Ul + gb0);
  uint4 rbl1 = *(const uint4*)(Ul + gb1);

  const f32x4 vz = {0.f, 0.f, 0.f, 0.f};
  f32x4 acc[4][4];
#pragma unroll
  for (int i = 0; i < 4; i++)
#pragma unroll
    for (int j = 0; j < 4; j++) acc[i][j] = vz;

  for (int kt = 0; kt < 16; kt++) {
    *(uint4*)&Ash[la0] = rah0; *(uint4*)&Ash[la1] = rah1;
    *(uint4*)&Asl[la0] = ral0; *(uint4*)&Asl[la1] = ral1;
    *(uint4*)&Bsh[la0] = rbh0; *(uint4*)&Bsh[la1] = rbh1;
    *(uint4*)&Bsl[la0] = rbl0; *(uint4*)&Bsl[la1] = rbl1;
    __syncthreads();
    if (kt < 15) {
      size_t ko = (size_t)(kt + 1) * 32;
      rah0 = *(const uint4*)(Xh + ga0 + ko); rah1 = *(const uint4*)(Xh + ga1 + ko);
      ral0 = *(const uint4*)(Xl + ga0 + ko); ral1 = *(const uint4*)(Xl + ga1 + ko);
      rbh0 = *(const uint4*)(Uh + gb0 + ko); rbh1 = *(const uint4*)(Uh + gb1 + ko);
      rbl0 = *(const uint4*)(Ul + gb0 + ko); rbl1 = *(const uint4*)(Ul + gb1 + ko);
    }
    short8 afh[4], afl[4], bfh[4], bfl[4];
#pragma unroll
    for (int mt = 0; mt < 4; mt++) {
      int idx = (kg * 128 + wm * 64 + mt * 16 + lr) * 8;
      afh[mt] = *(const short8*)&Ash[idx];
      afl[mt] = *(const short8*)&Asl[idx];
    }
#pragma unroll
    for (int nt = 0; nt < 4; nt++) {
      int idx = (kg * 128 + wn * 64 + nt * 16 + lr) * 8;
      bfh[nt] = *(const short8*)&Bsh[idx];
      bfl[nt] = *(const short8*)&Bsl[idx];
    }
#pragma unroll
    for (int mt = 0; mt < 4; mt++)
#pragma unroll
      for (int nt = 0; nt < 4; nt++) {
        acc[mt][nt] = __builtin_amdgcn_mfma_f32_16x16x32_bf16(afh[mt], bfh[nt], acc[mt][nt], 0, 0, 0);
        acc[mt][nt] = __builtin_amdgcn_mfma_f32_16x16x32_bf16(afh[mt], bfl[nt], acc[mt][nt], 0, 0, 0);
        acc[mt][nt] = __builtin_amdgcn_mfma_f32_16x16x32_bf16(afl[mt], bfh[nt], acc[mt][nt], 0, 0, 0);
      }
    __syncthreads();
  }
#pragma unroll
  for (int mt = 0; mt < 4; mt++) {
#pragma unroll
    for (int nt = 0; nt < 4; nt++) {
      int col = bn * 128 + wn * 64 + nt * 16 + lr;
      float bv = bias[col];
#pragma unroll
      for (int r = 0; r < 4; r++) {
        int row = bm * 128 + wm * 64 + mt * 16 + kg * 4 + r;
        Pb[(size_t)row * N3 + col] = (PT)(acc[mt][nt][r] + bv);
      }
    }
  }
}

// ---------------- persistent recurrent scan (tagged self-validating h exchange) ----------------
// 128 blocks x 512 thr (8 waves). Block (rg = blk>>5: 16 rows, cb = blk&31: 32 h-cols, BOTH mats).
// h word u32 = hi_bf16<<16 | (lo_bf16 & ~7) | (step&7). Producer: one relaxed agent u64 atomic
// store per thread, NO drain/flag. Consumer: sc0/sc1 dwordx4 tagged-retry loads (self-sync).
// Safety: ping-pong slot + 3-bit tag; block barriers order each block's stores after its loads,
// so a polled word can only hold h_t or h_{t-2} (tags always distinct mod 8).
template<typename PT>
__global__ __launch_bounds__(512, 1) void scan_kernel(const PT* __restrict__ P,
                                                      const u16* __restrict__ Wh,
                                                      const u16* __restrict__ Wl,
                                                      const float* __restrict__ h0,
                                                      u32* __restrict__ Hs,
                                                      float* __restrict__ out) {
  __shared__ float ex[2][8][16][36];   // [mat][kq][row][col pad36]
  const int tid = threadIdx.x;
  const int blk = blockIdx.x;
  const int cb = blk & 31, rg = blk >> 5;
  const int c0 = cb * 32, r0 = rg * 16;
  const int w = tid >> 6, l = tid & 63;   // w = K-eighth
  const int lr = l & 15, lk = l >> 4;

  // W fragments -> VGPRs (128 regs), held across all 512 steps
  short8 bwh[2][2][4], bwl[2][2][4];   // [mat][coltile][ktile]
#pragma unroll
  for (int m = 0; m < 2; m++)
#pragma unroll
    for (int ct = 0; ct < 2; ct++) {
      const size_t woff = ((size_t)m << 20) + (size_t)(c0 + ct * 16 + lr) * HDIM + w * 128 + lk * 8;
#pragma unroll
      for (int s = 0; s < 4; s++) {
        bwh[m][ct][s] = *(const short8*)(Wh + woff + s * 32);
        bwl[m][ct][s] = *(const short8*)(Wl + woff + s * 32);
      }
    }

  // elementwise ownership (tid<256): thread -> (row er of 16, col pair cq of 16); exact f32 state
  const int er = (tid & 255) >> 4;       // 0..15
  const int cq = tid & 15;               // 0..15
  const int gr = r0 + er;
  const int gc = c0 + cq * 2;
  float hs0 = 0.f, hs1 = 0.f;
  if (tid < 256) {
    hs0 = h0[(size_t)gr * HDIM + gc];
    hs1 = h0[(size_t)gr * HDIM + gc + 1];
  }

  const f32x4 vz = {0.f, 0.f, 0.f, 0.f};
  u32 budget = 1u << 18;   // retry budget across kernel (anti-hang)

#pragma unroll 1
  for (int t = 0; t < T_STEPS; t++) {
    // prefetch this step's projections (independent of h; overlaps retry loads)
    float xc0 = 0.f, xc1 = 0.f, xa0 = 0.f, xa1 = 0.f, xh0 = 0.f, xh1 = 0.f;
    if (tid < 256) {
      const PT* prow = P + (size_t)(t * BATCH + gr) * N3 + gc;
      xc0 = (float)prow[0];        xc1 = (float)prow[1];
      xa0 = (float)prow[HDIM];     xa1 = (float)prow[HDIM + 1];
      xh0 = (float)prow[2 * HDIM]; xh1 = (float)prow[2 * HDIM + 1];
    }

    // tagged self-validating h loads (sc0/sc1 bypass, retry until all 32 tags == t&7)
    const u32* hp = Hs + ((size_t)(t & 1) << 16) + (size_t)(r0 + lr) * HDIM + w * 128 + lk * 8;
    u32x4 pw[8];
    const u32 want = (u32)(t & 7);
    for (;;) {
#pragma unroll
      for (int s = 0; s < 4; s++) {
        asm volatile("global_load_dwordx4 %0, %1, off sc0 sc1"
                     : "=&v"(pw[2 * s]) : "v"(hp + s * 32) : "memory");
        asm volatile("global_load_dwordx4 %0, %1, off sc0 sc1"
                     : "=&v"(pw[2 * s + 1]) : "v"(hp + s * 32 + 4) : "memory");
      }
      asm volatile("s_waitcnt vmcnt(0)" ::: "memory");
      bool ok = true;
#pragma unroll
      for (int i = 0; i < 8; i++)
#pragma unroll
        for (int j = 0; j < 4; j++) ok &= ((pw[i][j] & 7u) == want);
      if (__all(ok) || --budget == 0u) break;
      __builtin_amdgcn_s_sleep(1);
    }
    __builtin_amdgcn_sched_barrier(0);

    // unpack packed words -> hi / lo bf16 fragments
    short8 hH[4], hL[4];
#pragma unroll
    for (int s = 0; s < 4; s++) {
      u32x4 a = pw[2 * s], b = pw[2 * s + 1];
      union { u32x4 u; short8 v; } uh, ul;
      uh.u[0] = (a[0] >> 16) | (a[1] & 0xFFFF0000u);
      uh.u[1] = (a[2] >> 16) | (a[3] & 0xFFFF0000u);
      uh.u[2] = (b[0] >> 16) | (b[1] & 0xFFFF0000u);
      uh.u[3] = (b[2] >> 16) | (b[3] & 0xFFFF0000u);
      ul.u[0] = (a[0] & 0xFFF8u) | ((a[1] & 0xFFF8u) << 16);
      ul.u[1] = (a[2] & 0xFFF8u) | ((a[3] & 0xFFF8u) << 16);
      ul.u[2] = (b[0] & 0xFFF8u) | ((b[1] & 0xFFF8u) << 16);
      ul.u[3] = (b[2] & 0xFFF8u) | ((b[3] & 0xFFF8u) << 16);
      hH[s] = uh.v;
      hL[s] = ul.v;
    }

    f32x4 acc[2][2];   // [mat][coltile]
    acc[0][0] = vz; acc[0][1] = vz; acc[1][0] = vz; acc[1][1] = vz;
#pragma unroll
    for (int s = 0; s < 4; s++) {
#pragma unroll
      for (int m = 0; m < 2; m++)
#pragma unroll
        for (int ct = 0; ct < 2; ct++) {
          acc[m][ct] = __builtin_amdgcn_mfma_f32_16x16x32_bf16(hH[s], bwh[m][ct][s], acc[m][ct], 0, 0, 0);
          acc[m][ct] = __builtin_amdgcn_mfma_f32_16x16x32_bf16(hH[s], bwl[m][ct][s], acc[m][ct], 0, 0, 0);
          acc[m][ct] = __builtin_amdgcn_mfma_f32_16x16x32_bf16(hL[s], bwh[m][ct][s], acc[m][ct], 0, 0, 0);
        }
    }

    __syncthreads();   // barrier A: prior step's elementwise done reading ex

    // scatter partial pre-activations (D: col=l&15, row=(l>>4)*4+r)
#pragma unroll
    for (int m = 0; m < 2; m++)
#pragma unroll
      for (int ct = 0; ct < 2; ct++)
#pragma unroll
        for (int r = 0; r < 4; r++)
          ex[m][w][lk * 4 + r][ct * 16 + lr] = acc[m][ct][r];
    __syncthreads();   // barrier B: partials visible

    if (tid < 256) {
      const int ec = cq * 2;
      float cp0 = xc0, cp1 = xc1, ap0 = xa0, ap1 = xa1;
#pragma unroll
      for (int q = 0; q < 8; q++) {
        cp0 += ex[0][q][er][ec];     cp1 += ex[0][q][er][ec + 1];
        ap0 += ex[1][q][er][ec];     ap1 += ex[1][q][er][ec + 1];
      }
      float c0g = fsigm(cp0), c1g = fsigm(cp1);
      float aa0 = 1.f + ftanh(ap0), aa1 = 1.f + ftanh(ap1);
      float th0 = ftanh(xh0 + aa0 * hs0), th1 = ftanh(xh1 + aa1 * hs1);
      float hn0 = c0g * hs0 + (1.f - c0g) * th0;
      float hn1 = c1g * hs1 + (1.f - c1g) * th1;
      hs0 = hn0; hs1 = hn1;

      // h_{t+1}: pack (hi, lo, tag) and release with ONE relaxed agent-scope u64 atomic
      const u32 tagn = (u32)((t + 1) & 7);
      u16 hb_0 = f2b(hn0), hb_1 = f2b(hn1);
      u16 lb_0 = f2b(hn0 - bf2f(hb_0)), lb_1 = f2b(hn1 - bf2f(hb_1));
      u32 w0 = ((u32)hb_0 << 16) | (u32)(lb_0 & 0xFFF8u) | tagn;
      u32 w1 = ((u32)hb_1 << 16) | (u32)(lb_1 & 0xFFF8u) | tagn;
      u64 wq = (u64)w0 | ((u64)w1 << 32);
      u64* hdst = (u64*)(Hs + ((size_t)((t + 1) & 1) << 16) + (size_t)gr * HDIM + gc);
      __hip_atomic_store(hdst, wq, __ATOMIC_RELAXED, __HIP_MEMORY_SCOPE_AGENT);

      // y output (off the critical path)
      float* yrow = out + (size_t)t * BATCH * HDIM + (size_t)gr * HDIM + gc;
      f32x2 y = {hn0, hn1};
      __builtin_nontemporal_store(y, (f32x2*)yrow);
      if (t == T_STEPS - 1) {
        float* frow = out + (size_t)T_STEPS * BATCH * HDIM + (size_t)gr * HDIM + gc;
        __builtin_nontemporal_store(y, (f32x2*)frow);
      }
    }
  }
}

// ---------------- launcher ----------------
static const size_t SZ_X1 = (size_t)TBm * IDIM * 2;      // 32 MB (hi or lo)
static const size_t SZ_U1 = (size_t)N3 * IDIM * 2;       // 3 MB
static const size_t SZ_W1 = (size_t)2 * HDIM * HDIM * 2; // 4 MB
static const size_t SZ_B  = (size_t)N3 * 4;
static const size_t SZ_HS = (size_t)2 * BATCH * HDIM * 4; // tagged packed h, 2 slots
static const size_t SZ_TAIL = 2*SZ_X1 + 2*SZ_U1 + 2*SZ_W1 + SZ_B + SZ_HS;

template<typename PT>
static void launch_path(void* const* d_in, float* out, char* ws, hipStream_t stream) {
  const float* x_seq = (const float*)d_in[0];
  const float* h0   = (const float*)d_in[1];
  const float* U_c  = (const float*)d_in[2];
  const float* W_c  = (const float*)d_in[3];
  const float* b_c  = (const float*)d_in[4];
  const float* U_a  = (const float*)d_in[5];
  const float* W_a  = (const float*)d_in[6];
  const float* b_a  = (const float*)d_in[7];
  const float* U_h  = (const float*)d_in[8];
  const float* b_h  = (const float*)d_in[9];

  const size_t szP = (size_t)TBm * N3 * sizeof(PT);
  PT*  Pb  = (PT*)(ws);
  u16* Xh  = (u16*)(ws + szP);
  u16* Xl  = (u16*)(ws + szP + SZ_X1);
  u16* Uh  = (u16*)(ws + szP + 2*SZ_X1);
  u16* Ul  = (u16*)(ws + szP + 2*SZ_X1 + SZ_U1);
  u16* Wh  = (u16*)(ws + szP + 2*SZ_X1 + 2*SZ_U1);
  u16* Wl  = (u16*)(ws + szP + 2*SZ_X1 + 2*SZ_U1 + SZ_W1);
  float* bias = (float*)(ws + szP + 2*SZ_X1 + 2*SZ_U1 + 2*SZ_W1);
  u32* Hs  = (u32*)((char*)bias + SZ_B);

  (void)hipMemcpyAsync(bias + 0 * HDIM, b_c, HDIM * sizeof(float), hipMemcpyDeviceToDevice, stream);
  (void)hipMemcpyAsync(bias + 1 * HDIM, b_a, HDIM * sizeof(float), hipMemcpyDeviceToDevice, stream);
  (void)hipMemcpyAsync(bias + 2 * HDIM, b_h, HDIM * sizeof(float), hipMemcpyDeviceToDevice, stream);

  int n4;
  n4 = TBm * IDIM / 4;
  split_f32<<<(n4 + 255) / 256, 256, 0, stream>>>(x_seq, Xh, Xl, n4);
  n4 = HDIM * IDIM / 4;
  split_f32<<<(n4 + 255) / 256, 256, 0, stream>>>(U_c, Uh + 0 * (size_t)HDIM * IDIM, Ul + 0 * (size_t)HDIM * IDIM, n4);
  split_f32<<<(n4 + 255) / 256, 256, 0, stream>>>(U_a, Uh + 1 * (size_t)HDIM * IDIM, Ul + 1 * (size_t)HDIM * IDIM, n4);
  split_f32<<<(n4 + 255) / 256, 256, 0, stream>>>(U_h, Uh + 2 * (size_t)HDIM * IDIM, Ul + 2 * (size_t)HDIM * IDIM, n4);
  n4 = HDIM * HDIM / 4;
  split_f32<<<(n4 + 255) / 256, 256, 0, stream>>>(W_c, Wh, Wl, n4);
  split_f32<<<(n4 + 255) / 256, 256, 0, stream>>>(W_a, Wh + (size_t)HDIM * HDIM, Wl + (size_t)HDIM * HDIM, n4);

  init_h<<<(BATCH * HDIM) / 256, 256, 0, stream>>>(h0, Hs);

  proj_gemm<PT><<<dim3(TBm / 128, N3 / 128), 256, 0, stream>>>(Xh, Xl, Uh, Ul, bias, Pb);
  scan_kernel<PT><<<NBLK, 512, 0, stream>>>(Pb, Wh, Wl, h0, Hs, out);
}

extern "C" void kernel_launch(void* const* d_in, const int* in_sizes, int n_in,
                              void* d_out, int out_size, void* d_ws, size_t ws_size,
                              hipStream_t stream) {
  const size_t need_f32 = (size_t)TBm * N3 * 4 + SZ_TAIL;   // ~481 MB
  const size_t need_f16 = (size_t)TBm * N3 * 2 + SZ_TAIL;   // ~271 MB

  if (ws_size >= need_f32) {
    launch_path<float>(d_in, (float*)d_out, (char*)d_ws, stream);
  } else if (ws_size >= need_f16) {
    launch_path<_Float16>(d_in, (float*)d_out, (char*)d_ws, stream);
  } else {
    float v = 1.0e6f + (float)(ws_size >> 20);   // sentinel: encodes ws MB
    ws_small_kernel<<<2048, 256, 0, stream>>>((float*)d_out, out_size, v);
  }
}

// Round 8
// 3665.359 us; speedup vs baseline: 1.0531x; 1.0531x over previous
//
#include <hip/hip_runtime.h>
#include <stdint.h>

typedef unsigned short u16;
typedef unsigned int u32;
typedef unsigned long long u64;
typedef short short8 __attribute__((ext_vector_type(8)));
typedef unsigned int u32x4 __attribute__((ext_vector_type(4)));
typedef float f32x4 __attribute__((ext_vector_type(4)));
typedef float f32x2 __attribute__((ext_vector_type(2)));

#define T_STEPS 512
#define BATCH 64
#define IDIM 512
#define HDIM 1024
#define TBm (T_STEPS*BATCH)      /* 32768 */
#define N3 (3*HDIM)              /* 3072 */
#define NBLK 128                 /* scan blocks: 4 row-groups x 32 col-blocks */

// ---------------- helpers ----------------
__device__ __forceinline__ float bf2f(u16 s) {
  union { u32 u; float f; } v; v.u = ((u32)s) << 16; return v.f;
}
__device__ __forceinline__ u16 f2b(float f) {
  union { float f; u32 u; } v; v.f = f;
  u32 u = v.u;
  u += 0x7fffu + ((u >> 16) & 1u);   // RNE
  return (u16)(u >> 16);
}
__device__ __forceinline__ float ftanh(float x) {
  x = fminf(20.f, fmaxf(-20.f, x));
  float e = __expf(2.f * x);
  return (e - 1.f) / (e + 1.f);
}
__device__ __forceinline__ float fsigm(float x) {
  x = fminf(30.f, fmaxf(-30.f, x));
  return 1.f / (1.f + __expf(-x));
}

// ---------------- f32 -> (bf16 hi, bf16 lo) split, 4 elems/thread ----------------
__global__ void split_f32(const float* __restrict__ src, u16* __restrict__ hi,
                          u16* __restrict__ lo, int n4) {
  int i = blockIdx.x * blockDim.x + threadIdx.x;
  if (i >= n4) return;
  float4 a = ((const float4*)src)[i];
  u16 h0 = f2b(a.x), h1 = f2b(a.y), h2 = f2b(a.z), h3 = f2b(a.w);
  u16 l0 = f2b(a.x - bf2f(h0)), l1 = f2b(a.y - bf2f(h1));
  u16 l2 = f2b(a.z - bf2f(h2)), l3 = f2b(a.w - bf2f(h3));
  uint2 hv; hv.x = (u32)h0 | ((u32)h1 << 16); hv.y = (u32)h2 | ((u32)h3 << 16);
  uint2 lv; lv.x = (u32)l0 | ((u32)l1 << 16); lv.y = (u32)l2 | ((u32)l3 << 16);
  ((uint2*)hi)[i] = hv;
  ((uint2*)lo)[i] = lv;
}

// ---------------- h0 -> tagged packed h (slot 0, tag 0) ----------------
__global__ void init_h(const float* __restrict__ h0, u32* __restrict__ Hs) {
  int i = blockIdx.x * blockDim.x + threadIdx.x;   // 0..65535
  float v = h0[i];
  u16 hb = f2b(v);
  u16 lb = f2b(v - bf2f(hb));
  Hs[i] = ((u32)hb << 16) | (u32)(lb & 0xFFF8u);   // tag = 0
}

// ---------------- ws-too-small sentinel ----------------
__global__ void ws_small_kernel(float* out, int n, float val) {
  int i = blockIdx.x * blockDim.x + threadIdx.x;
  for (; i < n; i += gridDim.x * blockDim.x) out[i] = val;
}

// ------------- projection GEMM (3-product split): P = Xh@Uh^T + Xh@Ul^T + Xl@Uh^T + b -------------
template<typename PT>
__global__ __launch_bounds__(256) void proj_gemm(const u16* __restrict__ Xh, const u16* __restrict__ Xl,
                                                 const u16* __restrict__ Uh, const u16* __restrict__ Ul,
                                                 const float* __restrict__ bias,
                                                 PT* __restrict__ Pb) {
  __shared__ u16 Ash[4096], Asl[4096], Bsh[4096], Bsl[4096];   // [kc=4][row=128][8]
  const int tid = threadIdx.x;
  const int bm = blockIdx.x, bn = blockIdx.y;
  const int w = tid >> 6, l = tid & 63;
  const int wm = w >> 1, wn = w & 1;
  const int lr = l & 15, kg = l >> 4;

  const int r0t = tid >> 2;           // 0..63
  const int kc = tid & 3;             // k-chunk 0..3
  const size_t ga0 = (size_t)(bm * 128 + r0t) * IDIM + kc * 8;
  const size_t ga1 = ga0 + (size_t)64 * IDIM;
  const size_t gb0 = (size_t)(bn * 128 + r0t) * IDIM + kc * 8;
  const size_t gb1 = gb0 + (size_t)64 * IDIM;
  const int la0 = (kc * 128 + r0t) * 8;
  const int la1 = la0 + 64 * 8;

  uint4 rah0 = *(const uint4*)(Xh + ga0);
  uint4 rah1 = *(const uint4*)(Xh + ga1);
  uint4 ral0 = *(const uint4*)(Xl + ga0);
  uint4 ral1 = *(const uint4*)(Xl + ga1);
  uint4 rbh0 = *(const uint4*)(Uh + gb0);
  uint4 rbh1 = *(const uint4*)(Uh + gb1);
  uint4 rbl0 = *(const uint4*)(Ul + gb0);
  uint4 rbl1 = *(const uint4*)(Ul + gb1);

  const f32x4 vz = {0.f, 0.f, 0.f, 0.f};
  f32x4 acc[4][4];
#pragma unroll
  for (int i = 0; i < 4; i++)
#pragma unroll
    for (int j = 0; j < 4; j++) acc[i][j] = vz;

  for (int kt = 0; kt < 16; kt++) {
    *(uint4*)&Ash[la0] = rah0; *(uint4*)&Ash[la1] = rah1;
    *(uint4*)&Asl[la0] = ral0; *(uint4*)&Asl[la1] = ral1;
    *(uint4*)&Bsh[la0] = rbh0; *(uint4*)&Bsh[la1] = rbh1;
    *(uint4*)&Bsl[la0] = rbl0; *(uint4*)&Bsl[la1] = rbl1;
    __syncthreads();
    if (kt < 15) {
      size_t ko = (size_t)(kt + 1) * 32;
      rah0 = *(const uint4*)(Xh + ga0 + ko); rah1 = *(const uint4*)(Xh + ga1 + ko);
      ral0 = *(const uint4*)(Xl + ga0 + ko); ral1 = *(const uint4*)(Xl + ga1 + ko);
      rbh0 = *(const uint4*)(Uh + gb0 + ko); rbh1 = *(const uint4*)(Uh + gb1 + ko);
      rbl0 = *(const uint4*)(Ul + gb0 + ko); rbl1 = *(const uint4*)(Ul + gb1 + ko);
    }
    short8 afh[4], afl[4], bfh[4], bfl[4];
#pragma unroll
    for (int mt = 0; mt < 4; mt++) {
      int idx = (kg * 128 + wm * 64 + mt * 16 + lr) * 8;
      afh[mt] = *(const short8*)&Ash[idx];
      afl[mt] = *(const short8*)&Asl[idx];
    }
#pragma unroll
    for (int nt = 0; nt < 4; nt++) {
      int idx = (kg * 128 + wn * 64 + nt * 16 + lr) * 8;
      bfh[nt] = *(const short8*)&Bsh[idx];
      bfl[nt] = *(const short8*)&Bsl[idx];
    }
#pragma unroll
    for (int mt = 0; mt < 4; mt++)
#pragma unroll
      for (int nt = 0; nt < 4; nt++) {
        acc[mt][nt] = __builtin_amdgcn_mfma_f32_16x16x32_bf16(afh[mt], bfh[nt], acc[mt][nt], 0, 0, 0);
        acc[mt][nt] = __builtin_amdgcn_mfma_f32_16x16x32_bf16(afh[mt], bfl[nt], acc[mt][nt], 0, 0, 0);
        acc[mt][nt] = __builtin_amdgcn_mfma_f32_16x16x32_bf16(afl[mt], bfh[nt], acc[mt][nt], 0, 0, 0);
      }
    __syncthreads();
  }
#pragma unroll
  for (int mt = 0; mt < 4; mt++) {
#pragma unroll
    for (int nt = 0; nt < 4; nt++) {
      int col = bn * 128 + wn * 64 + nt * 16 + lr;
      float bv = bias[col];
#pragma unroll
      for (int r = 0; r < 4; r++) {
        int row = bm * 128 + wm * 64 + mt * 16 + kg * 4 + r;
        Pb[(size_t)row * N3 + col] = (PT)(acc[mt][nt][r] + bv);
      }
    }
  }
}

// ---------------- persistent recurrent scan ----------------
// 128 blocks x 512 thr (8 waves). Block (rg = blk>>5: 16 rows, cb = blk&31: 32 h-cols, BOTH mats).
// Protocol: producer issues tagged h stores (relaxed agent u64 atomics), raw s_barrier (NO drain),
// tid0 sets flag. Consumer: ONE speculative tagged-data load; if stale -> tiny flag poll (per wave)
// then reload. Tags (3 low bits of lo-bf16, = t&7) make the flag a hint, the data self-validating.
// W pinned in VGPRs via opaque asm (prevents per-step rematerialized reloads from L2).
template<typename PT>
__global__ __launch_bounds__(512, 1) void scan_kernel(const PT* __restrict__ P,
                                                      const u16* __restrict__ Wh,
                                                      const u16* __restrict__ Wl,
                                                      const float* __restrict__ h0,
                                                      u32* __restrict__ Hs,
                                                      u32* __restrict__ flags,
                                                      float* __restrict__ out) {
  __shared__ float ex[2][2][8][16][36];   // [buf][mat][kq][row][col pad36]
  const int tid = threadIdx.x;
  const int blk = blockIdx.x;
  const int cb = blk & 31, rg = blk >> 5;
  const int c0 = cb * 32, r0 = rg * 16;
  const int w = tid >> 6, l = tid & 63;   // w = K-eighth
  const int lr = l & 15, lk = l >> 4;

  // W fragments -> VGPRs (128 regs), held across all 512 steps
  short8 bwh[2][2][4], bwl[2][2][4];   // [mat][coltile][ktile]
#pragma unroll
  for (int m = 0; m < 2; m++)
#pragma unroll
    for (int ct = 0; ct < 2; ct++) {
      const size_t woff = ((size_t)m << 20) + (size_t)(c0 + ct * 16 + lr) * HDIM + w * 128 + lk * 8;
#pragma unroll
      for (int s = 0; s < 4; s++) {
        bwh[m][ct][s] = *(const short8*)(Wh + woff + s * 32);
        bwl[m][ct][s] = *(const short8*)(Wl + woff + s * 32);
      }
    }
  // pin: opaque def -> compiler cannot rematerialize by re-loading; stays in VGPRs
#pragma unroll
  for (int m = 0; m < 2; m++)
#pragma unroll
    for (int ct = 0; ct < 2; ct++)
#pragma unroll
      for (int s = 0; s < 4; s++)
        asm volatile("" : "+v"(bwh[m][ct][s]), "+v"(bwl[m][ct][s]));

  // elementwise ownership (tid<256): thread -> (row er of 16, col pair cq of 16); exact f32 state
  const int er = (tid & 255) >> 4;       // 0..15
  const int cq = tid & 15;               // 0..15
  const int gr = r0 + er;
  const int gc = c0 + cq * 2;
  float hs0 = 0.f, hs1 = 0.f;
  if (tid < 256) {
    hs0 = h0[(size_t)gr * HDIM + gc];
    hs1 = h0[(size_t)gr * HDIM + gc + 1];
  }

  const f32x4 vz = {0.f, 0.f, 0.f, 0.f};
  u32 budget = 1u << 18;   // retry budget across kernel (anti-hang)

#pragma unroll 1
  for (int t = 0; t < T_STEPS; t++) {
    // prefetch this step's projections (independent of h; overlaps load/poll)
    float xc0 = 0.f, xc1 = 0.f, xa0 = 0.f, xa1 = 0.f, xh0 = 0.f, xh1 = 0.f;
    if (tid < 256) {
      const PT* prow = P + (size_t)(t * BATCH + gr) * N3 + gc;
      xc0 = (float)prow[0];        xc1 = (float)prow[1];
      xa0 = (float)prow[HDIM];     xa1 = (float)prow[HDIM + 1];
      xh0 = (float)prow[2 * HDIM]; xh1 = (float)prow[2 * HDIM + 1];
    }

    // speculative tagged h load; fallback: tiny flag poll, then reload (per wave, no block barrier)
    const u32* hp = Hs + ((size_t)(t & 1) << 16) + (size_t)(r0 + lr) * HDIM + w * 128 + lk * 8;
    const u32 want = (u32)(t & 7);
    u32x4 pw[8];
    for (;;) {
#pragma unroll
      for (int s = 0; s < 4; s++) {
        asm volatile("global_load_dwordx4 %0, %1, off sc0 sc1"
                     : "=&v"(pw[2 * s]) : "v"(hp + s * 32) : "memory");
        asm volatile("global_load_dwordx4 %0, %1, off sc0 sc1"
                     : "=&v"(pw[2 * s + 1]) : "v"(hp + s * 32 + 4) : "memory");
      }
      asm volatile("s_waitcnt vmcnt(0)" ::: "memory");
      bool ok = true;
#pragma unroll
      for (int i = 0; i < 8; i++)
#pragma unroll
        for (int j = 0; j < 4; j++) ok &= ((pw[i][j] & 7u) == want);
      if (__all(ok) || budget == 0u) break;
      // stale: wait on flags (tiny traffic) before reloading data
      if (t > 0) {
        const u32* fp = flags + (size_t)t * 128 + rg * 32 + (l & 31);
        for (;;) {
          u32 v = __hip_atomic_load(fp, __ATOMIC_RELAXED, __HIP_MEMORY_SCOPE_AGENT);
          if (__all(v != 0u) || budget == 0u) break;
          --budget;
          __builtin_amdgcn_s_sleep(1);
        }
      }
      if (budget) --budget;
    }
    __builtin_amdgcn_sched_barrier(0);

    // unpack + MFMA (per k-slice so pw registers die early)
    f32x4 acc[2][2];   // [mat][coltile]
    acc[0][0] = vz; acc[0][1] = vz; acc[1][0] = vz; acc[1][1] = vz;
#pragma unroll
    for (int s = 0; s < 4; s++) {
      u32x4 a = pw[2 * s], b = pw[2 * s + 1];
      union { u32x4 u; short8 v; } uh, ul;
      uh.u[0] = (a[0] >> 16) | (a[1] & 0xFFFF0000u);
      uh.u[1] = (a[2] >> 16) | (a[3] & 0xFFFF0000u);
      uh.u[2] = (b[0] >> 16) | (b[1] & 0xFFFF0000u);
      uh.u[3] = (b[2] >> 16) | (b[3] & 0xFFFF0000u);
      ul.u[0] = (a[0] & 0xFFF8u) | ((a[1] & 0xFFF8u) << 16);
      ul.u[1] = (a[2] & 0xFFF8u) | ((a[3] & 0xFFF8u) << 16);
      ul.u[2] = (b[0] & 0xFFF8u) | ((b[1] & 0xFFF8u) << 16);
      ul.u[3] = (b[2] & 0xFFF8u) | ((b[3] & 0xFFF8u) << 16);
#pragma unroll
      for (int m = 0; m < 2; m++)
#pragma unroll
        for (int ct = 0; ct < 2; ct++) {
          acc[m][ct] = __builtin_amdgcn_mfma_f32_16x16x32_bf16(uh.v, bwh[m][ct][s], acc[m][ct], 0, 0, 0);
          acc[m][ct] = __builtin_amdgcn_mfma_f32_16x16x32_bf16(uh.v, bwl[m][ct][s], acc[m][ct], 0, 0, 0);
          acc[m][ct] = __builtin_amdgcn_mfma_f32_16x16x32_bf16(ul.v, bwh[m][ct][s], acc[m][ct], 0, 0, 0);
        }
    }

    // scatter partial pre-activations into this step's ex buffer (D: col=l&15, row=(l>>4)*4+r)
#pragma unroll
    for (int m = 0; m < 2; m++)
#pragma unroll
      for (int ct = 0; ct < 2; ct++)
#pragma unroll
        for (int r = 0; r < 4; r++)
          ex[t & 1][m][w][lk * 4 + r][ct * 16 + lr] = acc[m][ct][r];
    __syncthreads();   // partials visible (double-buffered ex: no pre-scatter barrier needed)

    if (tid < 256) {
      const int ec = cq * 2;
      float cp0 = xc0, cp1 = xc1, ap0 = xa0, ap1 = xa1;
#pragma unroll
      for (int q = 0; q < 8; q++) {
        cp0 += ex[t & 1][0][q][er][ec];     cp1 += ex[t & 1][0][q][er][ec + 1];
        ap0 += ex[t & 1][1][q][er][ec];     ap1 += ex[t & 1][1][q][er][ec + 1];
      }
      float c0g = fsigm(cp0), c1g = fsigm(cp1);
      float aa0 = 1.f + ftanh(ap0), aa1 = 1.f + ftanh(ap1);
      float th0 = ftanh(xh0 + aa0 * hs0), th1 = ftanh(xh1 + aa1 * hs1);
      float hn0 = c0g * hs0 + (1.f - c0g) * th0;
      float hn1 = c1g * hs1 + (1.f - c1g) * th1;
      hs0 = hn0; hs1 = hn1;

      // h_{t+1}: pack (hi, lo, tag), ONE relaxed agent-scope u64 atomic store (no drain)
      const u32 tagn = (u32)((t + 1) & 7);
      u16 hb_0 = f2b(hn0), hb_1 = f2b(hn1);
      u16 lb_0 = f2b(hn0 - bf2f(hb_0)), lb_1 = f2b(hn1 - bf2f(hb_1));
      u32 w0 = ((u32)hb_0 << 16) | (u32)(lb_0 & 0xFFF8u) | tagn;
      u32 w1 = ((u32)hb_1 << 16) | (u32)(lb_1 & 0xFFF8u) | tagn;
      u64 wq = (u64)w0 | ((u64)w1 << 32);
      u64* hdst = (u64*)(Hs + ((size_t)((t + 1) & 1) << 16) + (size_t)gr * HDIM + gc);
      __hip_atomic_store(hdst, wq, __ATOMIC_RELAXED, __HIP_MEMORY_SCOPE_AGENT);
    }

    // raw barrier (NO vmcnt drain): all lanes have ISSUED h stores; tags cover in-flight races
    __builtin_amdgcn_sched_barrier(0);
    __builtin_amdgcn_s_barrier();
    __builtin_amdgcn_sched_barrier(0);
    if (tid == 0)
      __hip_atomic_store(flags + (size_t)(t + 1) * 128 + rg * 32 + cb, 1u,
                         __ATOMIC_RELAXED, __HIP_MEMORY_SCOPE_AGENT);

    // y output (fully off the critical path)
    if (tid < 256) {
      float hn0 = hs0, hn1 = hs1;
      float* yrow = out + (size_t)t * BATCH * HDIM + (size_t)gr * HDIM + gc;
      f32x2 y = {hn0, hn1};
      __builtin_nontemporal_store(y, (f32x2*)yrow);
      if (t == T_STEPS - 1) {
        float* frow = out + (size_t)T_STEPS * BATCH * HDIM + (size_t)gr * HDIM + gc;
        __builtin_nontemporal_store(y, (f32x2*)frow);
      }
    }
  }
}

// ---------------- launcher ----------------
static const size_t SZ_X1 = (size_t)TBm * IDIM * 2;      // 32 MB (hi or lo)
static const size_t SZ_U1 = (size_t)N3 * IDIM * 2;       // 3 MB
static const size_t SZ_W1 = (size_t)2 * HDIM * HDIM * 2; // 4 MB
static const size_t SZ_B  = (size_t)N3 * 4;
static const size_t SZ_HS = (size_t)2 * BATCH * HDIM * 4; // tagged packed h, 2 slots
static const size_t SZ_F  = (size_t)(T_STEPS + 1) * 128 * 4;
static const size_t SZ_TAIL = 2*SZ_X1 + 2*SZ_U1 + 2*SZ_W1 + SZ_B + SZ_HS + SZ_F;

template<typename PT>
static void launch_path(void* const* d_in, float* out, char* ws, hipStream_t stream) {
  const float* x_seq = (const float*)d_in[0];
  const float* h0   = (const float*)d_in[1];
  const float* U_c  = (const float*)d_in[2];
  const float* W_c  = (const float*)d_in[3];
  const float* b_c  = (const float*)d_in[4];
  const float* U_a  = (const float*)d_in[5];
  const float* W_a  = (const float*)d_in[6];
  const float* b_a  = (const float*)d_in[7];
  const float* U_h  = (const float*)d_in[8];
  const float* b_h  = (const float*)d_in[9];

  const size_t szP = (size_t)TBm * N3 * sizeof(PT);
  PT*  Pb  = (PT*)(ws);
  u16* Xh  = (u16*)(ws + szP);
  u16* Xl  = (u16*)(ws + szP + SZ_X1);
  u16* Uh  = (u16*)(ws + szP + 2*SZ_X1);
  u16* Ul  = (u16*)(ws + szP + 2*SZ_X1 + SZ_U1);
  u16* Wh  = (u16*)(ws + szP + 2*SZ_X1 + 2*SZ_U1);
  u16* Wl  = (u16*)(ws + szP + 2*SZ_X1 + 2*SZ_U1 + SZ_W1);
  float* bias = (float*)(ws + szP + 2*SZ_X1 + 2*SZ_U1 + 2*SZ_W1);
  u32* Hs  = (u32*)((char*)bias + SZ_B);
  u32* Fl  = (u32*)((char*)bias + SZ_B + SZ_HS);

  (void)hipMemsetAsync(Fl, 0, SZ_F, stream);
  (void)hipMemcpyAsync(bias + 0 * HDIM, b_c, HDIM * sizeof(float), hipMemcpyDeviceToDevice, stream);
  (void)hipMemcpyAsync(bias + 1 * HDIM, b_a, HDIM * sizeof(float), hipMemcpyDeviceToDevice, stream);
  (void)hipMemcpyAsync(bias + 2 * HDIM, b_h, HDIM * sizeof(float), hipMemcpyDeviceToDevice, stream);

  int n4;
  n4 = TBm * IDIM / 4;
  split_f32<<<(n4 + 255) / 256, 256, 0, stream>>>(x_seq, Xh, Xl, n4);
  n4 = HDIM * IDIM / 4;
  split_f32<<<(n4 + 255) / 256, 256, 0, stream>>>(U_c, Uh + 0 * (size_t)HDIM * IDIM, Ul + 0 * (size_t)HDIM * IDIM, n4);
  split_f32<<<(n4 + 255) / 256, 256, 0, stream>>>(U_a, Uh + 1 * (size_t)HDIM * IDIM, Ul + 1 * (size_t)HDIM * IDIM, n4);
  split_f32<<<(n4 + 255) / 256, 256, 0, stream>>>(U_h, Uh + 2 * (size_t)HDIM * IDIM, Ul + 2 * (size_t)HDIM * IDIM, n4);
  n4 = HDIM * HDIM / 4;
  split_f32<<<(n4 + 255) / 256, 256, 0, stream>>>(W_c, Wh, Wl, n4);
  split_f32<<<(n4 + 255) / 256, 256, 0, stream>>>(W_a, Wh + (size_t)HDIM * HDIM, Wl + (size_t)HDIM * HDIM, n4);

  init_h<<<(BATCH * HDIM) / 256, 256, 0, stream>>>(h0, Hs);

  proj_gemm<PT><<<dim3(TBm / 128, N3 / 128), 256, 0, stream>>>(Xh, Xl, Uh, Ul, bias, Pb);
  scan_kernel<PT><<<NBLK, 512, 0, stream>>>(Pb, Wh, Wl, h0, Hs, Fl, out);
}

extern "C" void kernel_launch(void* const* d_in, const int* in_sizes, int n_in,
                              void* d_out, int out_size, void* d_ws, size_t ws_size,
                              hipStream_t stream) {
  const size_t need_f32 = (size_t)TBm * N3 * 4 + SZ_TAIL;   // ~482 MB
  const size_t need_f16 = (size_t)TBm * N3 * 2 + SZ_TAIL;   // ~272 MB

  if (ws_size >= need_f32) {
    launch_path<float>(d_in, (float*)d_out, (char*)d_ws, stream);
  } else if (ws_size >= need_f16) {
    launch_path<_Float16>(d_in, (float*)d_out, (char*)d_ws, stream);
  } else {
    float v = 1.0e6f + (float)(ws_size >> 20);   // sentinel: encodes ws MB
    ws_small_kernel<<<2048, 256, 0, stream>>>((float*)d_out, out_size, v);
  }
}

// Round 9
// 3425.521 us; speedup vs baseline: 1.1268x; 1.0700x over previous
//
#include <hip/hip_runtime.h>
#include <stdint.h>

typedef unsigned short u16;
typedef unsigned int u32;
typedef unsigned long long u64;
typedef short short8 __attribute__((ext_vector_type(8)));
typedef unsigned int u32x4 __attribute__((ext_vector_type(4)));
typedef float f32x4 __attribute__((ext_vector_type(4)));
typedef float f32x2 __attribute__((ext_vector_type(2)));

#define T_STEPS 512
#define BATCH 64
#define IDIM 512
#define HDIM 1024
#define TBm (T_STEPS*BATCH)      /* 32768 */
#define N3 (3*HDIM)              /* 3072 */
#define NBLK 128                 /* scan blocks: 4 row-groups x 32 col-blocks */

// ---------------- helpers ----------------
__device__ __forceinline__ float bf2f(u16 s) {
  union { u32 u; float f; } v; v.u = ((u32)s) << 16; return v.f;
}
__device__ __forceinline__ u16 f2b(float f) {
  union { float f; u32 u; } v; v.f = f;
  u32 u = v.u;
  u += 0x7fffu + ((u >> 16) & 1u);   // RNE
  return (u16)(u >> 16);
}
__device__ __forceinline__ float ftanh(float x) {
  x = fminf(20.f, fmaxf(-20.f, x));
  float e = __expf(2.f * x);
  return (e - 1.f) / (e + 1.f);
}
__device__ __forceinline__ float fsigm(float x) {
  x = fminf(30.f, fmaxf(-30.f, x));
  return 1.f / (1.f + __expf(-x));
}

// ---------------- f32 -> (bf16 hi, bf16 lo) split, 4 elems/thread ----------------
__global__ void split_f32(const float* __restrict__ src, u16* __restrict__ hi,
                          u16* __restrict__ lo, int n4) {
  int i = blockIdx.x * blockDim.x + threadIdx.x;
  if (i >= n4) return;
  float4 a = ((const float4*)src)[i];
  u16 h0 = f2b(a.x), h1 = f2b(a.y), h2 = f2b(a.z), h3 = f2b(a.w);
  u16 l0 = f2b(a.x - bf2f(h0)), l1 = f2b(a.y - bf2f(h1));
  u16 l2 = f2b(a.z - bf2f(h2)), l3 = f2b(a.w - bf2f(h3));
  uint2 hv; hv.x = (u32)h0 | ((u32)h1 << 16); hv.y = (u32)h2 | ((u32)h3 << 16);
  uint2 lv; lv.x = (u32)l0 | ((u32)l1 << 16); lv.y = (u32)l2 | ((u32)l3 << 16);
  ((uint2*)hi)[i] = hv;
  ((uint2*)lo)[i] = lv;
}

// ---------------- h0 -> tagged packed h; BOTH slots rewritten each launch ----------------
// slot 0: h_0 values, tag 0 (wanted at t=0). slot 1: tag 4 — odd steps want odd tags, so this
// can never false-match; kills prior-replay residue deterministically.
__global__ void init_h(const float* __restrict__ h0, u32* __restrict__ Hs) {
  int i = blockIdx.x * blockDim.x + threadIdx.x;   // 0..65535
  float v = h0[i];
  u16 hb = f2b(v);
  u16 lb = f2b(v - bf2f(hb));
  Hs[i] = ((u32)hb << 16) | (u32)(lb & 0xFFF8u);          // tag = 0
  Hs[i + BATCH * HDIM] = 4u;                              // tag = 4 sentinel
}

// ---------------- ws-too-small sentinel ----------------
__global__ void ws_small_kernel(float* out, int n, float val) {
  int i = blockIdx.x * blockDim.x + threadIdx.x;
  for (; i < n; i += gridDim.x * blockDim.x) out[i] = val;
}

// ------------- projection GEMM (3-product split): P = Xh@Uh^T + Xh@Ul^T + Xl@Uh^T + b -------------
template<typename PT>
__global__ __launch_bounds__(256) void proj_gemm(const u16* __restrict__ Xh, const u16* __restrict__ Xl,
                                                 const u16* __restrict__ Uh, const u16* __restrict__ Ul,
                                                 const float* __restrict__ bias,
                                                 PT* __restrict__ Pb) {
  __shared__ u16 Ash[4096], Asl[4096], Bsh[4096], Bsl[4096];   // [kc=4][row=128][8]
  const int tid = threadIdx.x;
  const int bm = blockIdx.x, bn = blockIdx.y;
  const int w = tid >> 6, l = tid & 63;
  const int wm = w >> 1, wn = w & 1;
  const int lr = l & 15, kg = l >> 4;

  const int r0t = tid >> 2;           // 0..63
  const int kc = tid & 3;             // k-chunk 0..3
  const size_t ga0 = (size_t)(bm * 128 + r0t) * IDIM + kc * 8;
  const size_t ga1 = ga0 + (size_t)64 * IDIM;
  const size_t gb0 = (size_t)(bn * 128 + r0t) * IDIM + kc * 8;
  const size_t gb1 = gb0 + (size_t)64 * IDIM;
  const int la0 = (kc * 128 + r0t) * 8;
  const int la1 = la0 + 64 * 8;

  uint4 rah0 = *(const uint4*)(Xh + ga0);
  uint4 rah1 = *(const uint4*)(Xh + ga1);
  uint4 ral0 = *(const uint4*)(Xl + ga0);
  uint4 ral1 = *(const uint4*)(Xl + ga1);
  uint4 rbh0 = *(const uint4*)(Uh + gb0);
  uint4 rbh1 = *(const uint4*)(Uh + gb1);
  uint4 rbl0 = *(const uint4*)(Ul + gb0);
  uint4 rbl1 = *(const uint4*)(Ul + gb1);

  const f32x4 vz = {0.f, 0.f, 0.f, 0.f};
  f32x4 acc[4][4];
#pragma unroll
  for (int i = 0; i < 4; i++)
#pragma unroll
    for (int j = 0; j < 4; j++) acc[i][j] = vz;

  for (int kt = 0; kt < 16; kt++) {
    *(uint4*)&Ash[la0] = rah0; *(uint4*)&Ash[la1] = rah1;
    *(uint4*)&Asl[la0] = ral0; *(uint4*)&Asl[la1] = ral1;
    *(uint4*)&Bsh[la0] = rbh0; *(uint4*)&Bsh[la1] = rbh1;
    *(uint4*)&Bsl[la0] = rbl0; *(uint4*)&Bsl[la1] = rbl1;
    __syncthreads();
    if (kt < 15) {
      size_t ko = (size_t)(kt + 1) * 32;
      rah0 = *(const uint4*)(Xh + ga0 + ko); rah1 = *(const uint4*)(Xh + ga1 + ko);
      ral0 = *(const uint4*)(Xl + ga0 + ko); ral1 = *(const uint4*)(Xl + ga1 + ko);
      rbh0 = *(const uint4*)(Uh + gb0 + ko); rbh1 = *(const uint4*)(Uh + gb1 + ko);
      rbl0 = *(const uint4*)(Ul + gb0 + ko); rbl1 = *(const uint4*)(Ul + gb1 + ko);
    }
    short8 afh[4], afl[4], bfh[4], bfl[4];
#pragma unroll
    for (int mt = 0; mt < 4; mt++) {
      int idx = (kg * 128 + wm * 64 + mt * 16 + lr) * 8;
      afh[mt] = *(const short8*)&Ash[idx];
      afl[mt] = *(const short8*)&Asl[idx];
    }
#pragma unroll
    for (int nt = 0; nt < 4; nt++) {
      int idx = (kg * 128 + wn * 64 + nt * 16 + lr) * 8;
      bfh[nt] = *(const short8*)&Bsh[idx];
      bfl[nt] = *(const short8*)&Bsl[idx];
    }
#pragma unroll
    for (int mt = 0; mt < 4; mt++)
#pragma unroll
      for (int nt = 0; nt < 4; nt++) {
        acc[mt][nt] = __builtin_amdgcn_mfma_f32_16x16x32_bf16(afh[mt], bfh[nt], acc[mt][nt], 0, 0, 0);
        acc[mt][nt] = __builtin_amdgcn_mfma_f32_16x16x32_bf16(afh[mt], bfl[nt], acc[mt][nt], 0, 0, 0);
        acc[mt][nt] = __builtin_amdgcn_mfma_f32_16x16x32_bf16(afl[mt], bfh[nt], acc[mt][nt], 0, 0, 0);
      }
    __syncthreads();
  }
#pragma unroll
  for (int mt = 0; mt < 4; mt++) {
#pragma unroll
    for (int nt = 0; nt < 4; nt++) {
      int col = bn * 128 + wn * 64 + nt * 16 + lr;
      float bv = bias[col];
#pragma unroll
      for (int r = 0; r < 4; r++) {
        int row = bm * 128 + wm * 64 + mt * 16 + kg * 4 + r;
        Pb[(size_t)row * N3 + col] = (PT)(acc[mt][nt][r] + bv);
      }
    }
  }
}

// ---------------- persistent recurrent scan (probe-gated tagged exchange) ----------------
// 128 blocks x 512 thr (8 waves). Block (rg = blk>>5: 16 rows, cb = blk&31: 32 h-cols, BOTH mats).
// Producer: elementwise -> tagged u64 relaxed agent stores ISSUED -> done. No drain/barrier/flag.
// Consumer wave w: probe ONE tagged u32 per needed producer (4, broadcast across lanes) until
// tag == t&7, THEN bulk tagged dwordx4 loads with micro-retry. Gating keeps poll traffic tiny
// (131 KB/step grid-wide) — the round-7/8 bulk-poll IC storm is structurally impossible.
template<typename PT>
__global__ __launch_bounds__(512, 1) void scan_kernel(const PT* __restrict__ P,
                                                      const u16* __restrict__ Wh,
                                                      const u16* __restrict__ Wl,
                                                      const float* __restrict__ h0,
                                                      u32* __restrict__ Hs,
                                                      float* __restrict__ out) {
  __shared__ float ex[2][2][8][16][36];   // [buf][mat][kq][row][col pad36]
  const int tid = threadIdx.x;
  const int blk = blockIdx.x;
  const int cb = blk & 31, rg = blk >> 5;
  const int c0 = cb * 32, r0 = rg * 16;
  const int w = tid >> 6, l = tid & 63;   // w = K-eighth
  const int lr = l & 15, lk = l >> 4;

  // W fragments -> VGPRs / L2 (compiler's choice), loop-invariant
  short8 bwh[2][2][4], bwl[2][2][4];   // [mat][coltile][ktile]
#pragma unroll
  for (int m = 0; m < 2; m++)
#pragma unroll
    for (int ct = 0; ct < 2; ct++) {
      const size_t woff = ((size_t)m << 20) + (size_t)(c0 + ct * 16 + lr) * HDIM + w * 128 + lk * 8;
#pragma unroll
      for (int s = 0; s < 4; s++) {
        bwh[m][ct][s] = *(const short8*)(Wh + woff + s * 32);
        bwl[m][ct][s] = *(const short8*)(Wl + woff + s * 32);
      }
    }

  // elementwise ownership (tid<256): thread -> (row er of 16, col pair cq of 16); exact f32 state
  const int er = (tid & 255) >> 4;       // 0..15
  const int cq = tid & 15;               // 0..15
  const int gr = r0 + er;
  const int gc = c0 + cq * 2;
  float hs0 = 0.f, hs1 = 0.f;
  if (tid < 256) {
    hs0 = h0[(size_t)gr * HDIM + gc];
    hs1 = h0[(size_t)gr * HDIM + gc + 1];
  }

  const f32x4 vz = {0.f, 0.f, 0.f, 0.f};
  u32 budget = 1u << 20;   // retry budget across kernel (anti-hang)

#pragma unroll 1
  for (int t = 0; t < T_STEPS; t++) {
    // prefetch this step's projections (independent of h; overlaps probe)
    float xc0 = 0.f, xc1 = 0.f, xa0 = 0.f, xa1 = 0.f, xh0 = 0.f, xh1 = 0.f;
    if (tid < 256) {
      const PT* prow = P + (size_t)(t * BATCH + gr) * N3 + gc;
      xc0 = (float)prow[0];        xc1 = (float)prow[1];
      xa0 = (float)prow[HDIM];     xa1 = (float)prow[HDIM + 1];
      xh0 = (float)prow[2 * HDIM]; xh1 = (float)prow[2 * HDIM + 1];
    }

    const u32 want = (u32)(t & 7);
    const size_t slot = (size_t)(t & 1) << 16;

    // ---- probe: 4 B/lane poll of one word per needed producer (4 producers/wave) ----
    {
      const u32* probe = Hs + slot + (size_t)r0 * HDIM + (size_t)(w * 128 + (l & 3) * 32);
      for (;;) {
        u32 v;
        asm volatile("global_load_dword %0, %1, off sc0 sc1"
                     : "=&v"(v) : "v"(probe) : "memory");
        asm volatile("s_waitcnt vmcnt(0)" ::: "memory");
        if (__all((v & 7u) == want) || budget == 0u) break;
        --budget;
        __builtin_amdgcn_s_sleep(1);
      }
    }

    // ---- bulk tagged load with micro-retry (rare: probe-ahead-of-data stragglers) ----
    const u32* hp = Hs + slot + (size_t)(r0 + lr) * HDIM + w * 128 + lk * 8;
    u32x4 pw[8];
    for (;;) {
#pragma unroll
      for (int s = 0; s < 4; s++) {
        asm volatile("global_load_dwordx4 %0, %1, off sc0 sc1"
                     : "=&v"(pw[2 * s]) : "v"(hp + s * 32) : "memory");
        asm volatile("global_load_dwordx4 %0, %1, off sc0 sc1"
                     : "=&v"(pw[2 * s + 1]) : "v"(hp + s * 32 + 4) : "memory");
      }
      asm volatile("s_waitcnt vmcnt(0)" ::: "memory");
      bool ok = true;
#pragma unroll
      for (int i = 0; i < 8; i++)
#pragma unroll
        for (int j = 0; j < 4; j++) ok &= ((pw[i][j] & 7u) == want);
      if (__all(ok) || budget == 0u) break;
      --budget;
      __builtin_amdgcn_s_sleep(1);
    }
    __builtin_amdgcn_sched_barrier(0);

    // unpack + MFMA (per k-slice so pw registers die early)
    f32x4 acc[2][2];   // [mat][coltile]
    acc[0][0] = vz; acc[0][1] = vz; acc[1][0] = vz; acc[1][1] = vz;
#pragma unroll
    for (int s = 0; s < 4; s++) {
      u32x4 a = pw[2 * s], b = pw[2 * s + 1];
      union { u32x4 u; short8 v; } uh, ul;
      uh.u[0] = (a[0] >> 16) | (a[1] & 0xFFFF0000u);
      uh.u[1] = (a[2] >> 16) | (a[3] & 0xFFFF0000u);
      uh.u[2] = (b[0] >> 16) | (b[1] & 0xFFFF0000u);
      uh.u[3] = (b[2] >> 16) | (b[3] & 0xFFFF0000u);
      ul.u[0] = (a[0] & 0xFFF8u) | ((a[1] & 0xFFF8u) << 16);
      ul.u[1] = (a[2] & 0xFFF8u) | ((a[3] & 0xFFF8u) << 16);
      ul.u[2] = (b[0] & 0xFFF8u) | ((b[1] & 0xFFF8u) << 16);
      ul.u[3] = (b[2] & 0xFFF8u) | ((b[3] & 0xFFF8u) << 16);
#pragma unroll
      for (int m = 0; m < 2; m++)
#pragma unroll
        for (int ct = 0; ct < 2; ct++) {
          acc[m][ct] = __builtin_amdgcn_mfma_f32_16x16x32_bf16(uh.v, bwh[m][ct][s], acc[m][ct], 0, 0, 0);
          acc[m][ct] = __builtin_amdgcn_mfma_f32_16x16x32_bf16(uh.v, bwl[m][ct][s], acc[m][ct], 0, 0, 0);
          acc[m][ct] = __builtin_amdgcn_mfma_f32_16x16x32_bf16(ul.v, bwh[m][ct][s], acc[m][ct], 0, 0, 0);
        }
    }

    // scatter partial pre-activations into this step's ex buffer (D: col=l&15, row=(l>>4)*4+r)
#pragma unroll
    for (int m = 0; m < 2; m++)
#pragma unroll
      for (int ct = 0; ct < 2; ct++)
#pragma unroll
        for (int r = 0; r < 4; r++)
          ex[t & 1][m][w][lk * 4 + r][ct * 16 + lr] = acc[m][ct][r];
    __syncthreads();   // partials visible (double-buffered ex: one barrier per step)

    if (tid < 256) {
      const int ec = cq * 2;
      float cp0 = xc0, cp1 = xc1, ap0 = xa0, ap1 = xa1;
#pragma unroll
      for (int q = 0; q < 8; q++) {
        cp0 += ex[t & 1][0][q][er][ec];     cp1 += ex[t & 1][0][q][er][ec + 1];
        ap0 += ex[t & 1][1][q][er][ec];     ap1 += ex[t & 1][1][q][er][ec + 1];
      }
      float c0g = fsigm(cp0), c1g = fsigm(cp1);
      float aa0 = 1.f + ftanh(ap0), aa1 = 1.f + ftanh(ap1);
      float th0 = ftanh(xh0 + aa0 * hs0), th1 = ftanh(xh1 + aa1 * hs1);
      float hn0 = c0g * hs0 + (1.f - c0g) * th0;
      float hn1 = c1g * hs1 + (1.f - c1g) * th1;
      hs0 = hn0; hs1 = hn1;

      // h_{t+1}: pack (hi, lo, tag), ONE relaxed agent-scope u64 atomic store — fire and forget
      const u32 tagn = (u32)((t + 1) & 7);
      u16 hb_0 = f2b(hn0), hb_1 = f2b(hn1);
      u16 lb_0 = f2b(hn0 - bf2f(hb_0)), lb_1 = f2b(hn1 - bf2f(hb_1));
      u32 w0 = ((u32)hb_0 << 16) | (u32)(lb_0 & 0xFFF8u) | tagn;
      u32 w1 = ((u32)hb_1 << 16) | (u32)(lb_1 & 0xFFF8u) | tagn;
      u64 wq = (u64)w0 | ((u64)w1 << 32);
      u64* hdst = (u64*)(Hs + ((size_t)((t + 1) & 1) << 16) + (size_t)gr * HDIM + gc);
      __hip_atomic_store(hdst, wq, __ATOMIC_RELAXED, __HIP_MEMORY_SCOPE_AGENT);

      // y output (off the critical path, after the h release)
      float* yrow = out + (size_t)t * BATCH * HDIM + (size_t)gr * HDIM + gc;
      f32x2 y = {hn0, hn1};
      __builtin_nontemporal_store(y, (f32x2*)yrow);
      if (t == T_STEPS - 1) {
        float* frow = out + (size_t)T_STEPS * BATCH * HDIM + (size_t)gr * HDIM + gc;
        __builtin_nontemporal_store(y, (f32x2*)frow);
      }
    }
  }
}

// ---------------- launcher ----------------
static const size_t SZ_X1 = (size_t)TBm * IDIM * 2;      // 32 MB (hi or lo)
static const size_t SZ_U1 = (size_t)N3 * IDIM * 2;       // 3 MB
static const size_t SZ_W1 = (size_t)2 * HDIM * HDIM * 2; // 4 MB
static const size_t SZ_B  = (size_t)N3 * 4;
static const size_t SZ_HS = (size_t)2 * BATCH * HDIM * 4; // tagged packed h, 2 slots
static const size_t SZ_TAIL = 2*SZ_X1 + 2*SZ_U1 + 2*SZ_W1 + SZ_B + SZ_HS;

template<typename PT>
static void launch_path(void* const* d_in, float* out, char* ws, hipStream_t stream) {
  const float* x_seq = (const float*)d_in[0];
  const float* h0   = (const float*)d_in[1];
  const float* U_c  = (const float*)d_in[2];
  const float* W_c  = (const float*)d_in[3];
  const float* b_c  = (const float*)d_in[4];
  const float* U_a  = (const float*)d_in[5];
  const float* W_a  = (const float*)d_in[6];
  const float* b_a  = (const float*)d_in[7];
  const float* U_h  = (const float*)d_in[8];
  const float* b_h  = (const float*)d_in[9];

  const size_t szP = (size_t)TBm * N3 * sizeof(PT);
  PT*  Pb  = (PT*)(ws);
  u16* Xh  = (u16*)(ws + szP);
  u16* Xl  = (u16*)(ws + szP + SZ_X1);
  u16* Uh  = (u16*)(ws + szP + 2*SZ_X1);
  u16* Ul  = (u16*)(ws + szP + 2*SZ_X1 + SZ_U1);
  u16* Wh  = (u16*)(ws + szP + 2*SZ_X1 + 2*SZ_U1);
  u16* Wl  = (u16*)(ws + szP + 2*SZ_X1 + 2*SZ_U1 + SZ_W1);
  float* bias = (float*)(ws + szP + 2*SZ_X1 + 2*SZ_U1 + 2*SZ_W1);
  u32* Hs  = (u32*)((char*)bias + SZ_B);

  (void)hipMemcpyAsync(bias + 0 * HDIM, b_c, HDIM * sizeof(float), hipMemcpyDeviceToDevice, stream);
  (void)hipMemcpyAsync(bias + 1 * HDIM, b_a, HDIM * sizeof(float), hipMemcpyDeviceToDevice, stream);
  (void)hipMemcpyAsync(bias + 2 * HDIM, b_h, HDIM * sizeof(float), hipMemcpyDeviceToDevice, stream);

  int n4;
  n4 = TBm * IDIM / 4;
  split_f32<<<(n4 + 255) / 256, 256, 0, stream>>>(x_seq, Xh, Xl, n4);
  n4 = HDIM * IDIM / 4;
  split_f32<<<(n4 + 255) / 256, 256, 0, stream>>>(U_c, Uh + 0 * (size_t)HDIM * IDIM, Ul + 0 * (size_t)HDIM * IDIM, n4);
  split_f32<<<(n4 + 255) / 256, 256, 0, stream>>>(U_a, Uh + 1 * (size_t)HDIM * IDIM, Ul + 1 * (size_t)HDIM * IDIM, n4);
  split_f32<<<(n4 + 255) / 256, 256, 0, stream>>>(U_h, Uh + 2 * (size_t)HDIM * IDIM, Ul + 2 * (size_t)HDIM * IDIM, n4);
  n4 = HDIM * HDIM / 4;
  split_f32<<<(n4 + 255) / 256, 256, 0, stream>>>(W_c, Wh, Wl, n4);
  split_f32<<<(n4 + 255) / 256, 256, 0, stream>>>(W_a, Wh + (size_t)HDIM * HDIM, Wl + (size_t)HDIM * HDIM, n4);

  init_h<<<(BATCH * HDIM) / 256, 256, 0, stream>>>(h0, Hs);

  proj_gemm<PT><<<dim3(TBm / 128, N3 / 128), 256, 0, stream>>>(Xh, Xl, Uh, Ul, bias, Pb);
  scan_kernel<PT><<<NBLK, 512, 0, stream>>>(Pb, Wh, Wl, h0, Hs, out);
}

extern "C" void kernel_launch(void* const* d_in, const int* in_sizes, int n_in,
                              void* d_out, int out_size, void* d_ws, size_t ws_size,
                              hipStream_t stream) {
  const size_t need_f32 = (size_t)TBm * N3 * 4 + SZ_TAIL;   // ~481 MB
  const size_t need_f16 = (size_t)TBm * N3 * 2 + SZ_TAIL;   // ~271 MB

  if (ws_size >= need_f32) {
    launch_path<float>(d_in, (float*)d_out, (char*)d_ws, stream);
  } else if (ws_size >= need_f16) {
    launch_path<_Float16>(d_in, (float*)d_out, (char*)d_ws, stream);
  } else {
    float v = 1.0e6f + (float)(ws_size >> 20);   // sentinel: encodes ws MB
    ws_small_kernel<<<2048, 256, 0, stream>>>((float*)d_out, out_size, v);
  }
}

// Round 11
// 2569.675 us; speedup vs baseline: 1.5021x; 1.3331x over previous
//
#include <hip/hip_runtime.h>
#include <stdint.h>

typedef unsigned short u16;
typedef unsigned int u32;
typedef unsigned long long u64;
typedef short short8 __attribute__((ext_vector_type(8)));
typedef float f32x4 __attribute__((ext_vector_type(4)));
typedef float f32x2 __attribute__((ext_vector_type(2)));

#define T_STEPS 512
#define BATCH 64
#define IDIM 512
#define HDIM 1024
#define TBm (T_STEPS*BATCH)      /* 32768 */
#define N3 (3*HDIM)              /* 3072 */
#define NBLK 128                 /* scan blocks: 4 row-groups x 32 col-blocks */

// ---------------- helpers ----------------
__device__ __forceinline__ float bf2f(u16 s) {
  union { u32 u; float f; } v; v.u = ((u32)s) << 16; return v.f;
}
__device__ __forceinline__ u16 f2b(float f) {
  union { float f; u32 u; } v; v.f = f;
  u32 u = v.u;
  u += 0x7fffu + ((u >> 16) & 1u);   // RNE
  return (u16)(u >> 16);
}
__device__ __forceinline__ float ftanh(float x) {
  x = fminf(20.f, fmaxf(-20.f, x));
  float e = __expf(2.f * x);
  return (e - 1.f) / (e + 1.f);
}
__device__ __forceinline__ float fsigm(float x) {
  x = fminf(30.f, fmaxf(-30.f, x));
  return 1.f / (1.f + __expf(-x));
}

// ---------------- f32 -> (bf16 hi, bf16 lo) split, 4 elems/thread ----------------
__global__ void split_f32(const float* __restrict__ src, u16* __restrict__ hi,
                          u16* __restrict__ lo, int n4) {
  int i = blockIdx.x * blockDim.x + threadIdx.x;
  if (i >= n4) return;
  float4 a = ((const float4*)src)[i];
  u16 h0 = f2b(a.x), h1 = f2b(a.y), h2 = f2b(a.z), h3 = f2b(a.w);
  u16 l0 = f2b(a.x - bf2f(h0)), l1 = f2b(a.y - bf2f(h1));
  u16 l2 = f2b(a.z - bf2f(h2)), l3 = f2b(a.w - bf2f(h3));
  uint2 hv; hv.x = (u32)h0 | ((u32)h1 << 16); hv.y = (u32)h2 | ((u32)h3 << 16);
  uint2 lv; lv.x = (u32)l0 | ((u32)l1 << 16); lv.y = (u32)l2 | ((u32)l3 << 16);
  ((uint2*)hi)[i] = hv;
  ((uint2*)lo)[i] = lv;
}

// ---------------- ws-too-small sentinel ----------------
__global__ void ws_small_kernel(float* out, int n, float val) {
  int i = blockIdx.x * blockDim.x + threadIdx.x;
  for (; i < n; i += gridDim.x * blockDim.x) out[i] = val;
}

// ------------- projection GEMM (3-product split): P = Xh@Uh^T + Xh@Ul^T + Xl@Uh^T + b -------------
template<typename PT>
__global__ __launch_bounds__(256) void proj_gemm(const u16* __restrict__ Xh, const u16* __restrict__ Xl,
                                                 const u16* __restrict__ Uh, const u16* __restrict__ Ul,
                                                 const float* __restrict__ bias,
                                                 PT* __restrict__ Pb) {
  __shared__ u16 Ash[4096], Asl[4096], Bsh[4096], Bsl[4096];   // [kc=4][row=128][8]
  const int tid = threadIdx.x;
  const int bm = blockIdx.x, bn = blockIdx.y;
  const int w = tid >> 6, l = tid & 63;
  const int wm = w >> 1, wn = w & 1;
  const int lr = l & 15, kg = l >> 4;

  const int r0t = tid >> 2;           // 0..63
  const int kc = tid & 3;             // k-chunk 0..3
  const size_t ga0 = (size_t)(bm * 128 + r0t) * IDIM + kc * 8;
  const size_t ga1 = ga0 + (size_t)64 * IDIM;
  const size_t gb0 = (size_t)(bn * 128 + r0t) * IDIM + kc * 8;
  const size_t gb1 = gb0 + (size_t)64 * IDIM;
  const int la0 = (kc * 128 + r0t) * 8;
  const int la1 = la0 + 64 * 8;

  uint4 rah0 = *(const uint4*)(Xh + ga0);
  uint4 rah1 = *(const uint4*)(Xh + ga1);
  uint4 ral0 = *(const uint4*)(Xl + ga0);
  uint4 ral1 = *(const uint4*)(Xl + ga1);
  uint4 rbh0 = *(const uint4*)(Uh + gb0);
  uint4 rbh1 = *(const uint4*)(Uh + gb1);
  uint4 rbl0 = *(const uint4*)(Ul + gb0);
  uint4 rbl1 = *(const uint4*)(Ul + gb1);

  const f32x4 vz = {0.f, 0.f, 0.f, 0.f};
  f32x4 acc[4][4];
#pragma unroll
  for (int i = 0; i < 4; i++)
#pragma unroll
    for (int j = 0; j < 4; j++) acc[i][j] = vz;

  for (int kt = 0; kt < 16; kt++) {
    *(uint4*)&Ash[la0] = rah0; *(uint4*)&Ash[la1] = rah1;
    *(uint4*)&Asl[la0] = ral0; *(uint4*)&Asl[la1] = ral1;
    *(uint4*)&Bsh[la0] = rbh0; *(uint4*)&Bsh[la1] = rbh1;
    *(uint4*)&Bsl[la0] = rbl0; *(uint4*)&Bsl[la1] = rbl1;
    __syncthreads();
    if (kt < 15) {
      size_t ko = (size_t)(kt + 1) * 32;
      rah0 = *(const uint4*)(Xh + ga0 + ko); rah1 = *(const uint4*)(Xh + ga1 + ko);
      ral0 = *(const uint4*)(Xl + ga0 + ko); ral1 = *(const uint4*)(Xl + ga1 + ko);
      rbh0 = *(const uint4*)(Uh + gb0 + ko); rbh1 = *(const uint4*)(Uh + gb1 + ko);
      rbl0 = *(const uint4*)(Ul + gb0 + ko); rbl1 = *(const uint4*)(Ul + gb1 + ko);
    }
    short8 afh[4], afl[4], bfh[4], bfl[4];
#pragma unroll
    for (int mt = 0; mt < 4; mt++) {
      int idx = (kg * 128 + wm * 64 + mt * 16 + lr) * 8;
      afh[mt] = *(const short8*)&Ash[idx];
      afl[mt] = *(const short8*)&Asl[idx];
    }
#pragma unroll
    for (int nt = 0; nt < 4; nt++) {
      int idx = (kg * 128 + wn * 64 + nt * 16 + lr) * 8;
      bfh[nt] = *(const short8*)&Bsh[idx];
      bfl[nt] = *(const short8*)&Bsl[idx];
    }
#pragma unroll
    for (int mt = 0; mt < 4; mt++)
#pragma unroll
      for (int nt = 0; nt < 4; nt++) {
        acc[mt][nt] = __builtin_amdgcn_mfma_f32_16x16x32_bf16(afh[mt], bfh[nt], acc[mt][nt], 0, 0, 0);
        acc[mt][nt] = __builtin_amdgcn_mfma_f32_16x16x32_bf16(afh[mt], bfl[nt], acc[mt][nt], 0, 0, 0);
        acc[mt][nt] = __builtin_amdgcn_mfma_f32_16x16x32_bf16(afl[mt], bfh[nt], acc[mt][nt], 0, 0, 0);
      }
    __syncthreads();
  }
#pragma unroll
  for (int mt = 0; mt < 4; mt++) {
#pragma unroll
    for (int nt = 0; nt < 4; nt++) {
      int col = bn * 128 + wn * 64 + nt * 16 + lr;
      float bv = bias[col];
#pragma unroll
      for (int r = 0; r < 4; r++) {
        int row = bm * 128 + wm * 64 + mt * 16 + kg * 4 + r;
        Pb[(size_t)row * N3 + col] = (PT)(acc[mt][nt][r] + bv);
      }
    }
  }
}

// ---------------- persistent recurrent scan (round-6 protocol, W pinned via asm) ----------------
// 128 blocks x 512 thr (8 waves). Block (rg = blk>>5: 16 rows, cb = blk&31: 32 h-cols, BOTH mats).
// Sync (EXACTLY round 6, known-pass): wave-0 polls all 32 producer flags -> __syncthreads ->
// sc0/sc1 bulk h loads -> MFMA -> scatter -> barrier A -> elementwise -> atomic h stores ->
// barrier B (vmcnt drain) -> tid0 flag. ONLY change vs round 6: W loaded via inline-asm
// global_load_dwordx4 (un-rematerializable -> 128 VGPRs of W stay resident; rounds 6-9 re-read
// W from L2 every step, VGPR_Count 104 proved it).
template<typename PT>
__global__ __launch_bounds__(512, 1) void scan_kernel(const PT* __restrict__ P,
                                                      const u16* __restrict__ Wh,
                                                      const u16* __restrict__ Wl,
                                                      const float* __restrict__ h0,
                                                      u16* __restrict__ Hh, u16* __restrict__ Hl,
                                                      u32* __restrict__ flags,
                                                      float* __restrict__ out) {
  __shared__ float ex[2][8][16][36];   // [mat][kq][row][col pad36]
  const int tid = threadIdx.x;
  const int blk = blockIdx.x;
  const int cb = blk & 31, rg = blk >> 5;
  const int c0 = cb * 32, r0 = rg * 16;
  const int w = tid >> 6, l = tid & 63;   // w = K-eighth
  const int lr = l & 15, lk = l >> 4;

  // W fragments -> VGPRs via inline-asm (cannot be rematerialized -> truly resident)
  short8 bwh[2][2][4], bwl[2][2][4];   // [mat][coltile][ktile]
#pragma unroll
  for (int m = 0; m < 2; m++)
#pragma unroll
    for (int ct = 0; ct < 2; ct++) {
      const size_t woff = ((size_t)m << 20) + (size_t)(c0 + ct * 16 + lr) * HDIM + w * 128 + lk * 8;
#pragma unroll
      for (int s = 0; s < 4; s++) {
        asm volatile("global_load_dwordx4 %0, %1, off"
                     : "=&v"(bwh[m][ct][s]) : "v"(Wh + woff + s * 32) : "memory");
        asm volatile("global_load_dwordx4 %0, %1, off"
                     : "=&v"(bwl[m][ct][s]) : "v"(Wl + woff + s * 32) : "memory");
      }
    }
  asm volatile("s_waitcnt vmcnt(0)" ::: "memory");
  __builtin_amdgcn_sched_barrier(0);

  // elementwise ownership (tid<256): thread -> (row er of 16, col pair cq of 16); exact f32 state
  const int er = (tid & 255) >> 4;       // 0..15
  const int cq = tid & 15;               // 0..15
  const int gr = r0 + er;
  const int gc = c0 + cq * 2;
  float hs0 = 0.f, hs1 = 0.f;
  if (tid < 256) {
    hs0 = h0[(size_t)gr * HDIM + gc];
    hs1 = h0[(size_t)gr * HDIM + gc + 1];
  }

  const f32x4 vz = {0.f, 0.f, 0.f, 0.f};
  u32 budget = 1u << 20;   // poll budget (anti-hang)

#pragma unroll 1
  for (int t = 0; t < T_STEPS; t++) {
    // prefetch this step's projections (independent of h; overlaps poll)
    float xc0 = 0.f, xc1 = 0.f, xa0 = 0.f, xa1 = 0.f, xh0 = 0.f, xh1 = 0.f;
    if (tid < 256) {
      const PT* prow = P + (size_t)(t * BATCH + gr) * N3 + gc;
      xc0 = (float)prow[0];        xc1 = (float)prow[1];
      xa0 = (float)prow[HDIM];     xa1 = (float)prow[HDIM + 1];
      xh0 = (float)prow[2 * HDIM]; xh1 = (float)prow[2 * HDIM + 1];
    }

    if (t > 0) {
      if (tid < 64) {   // wave 0: parallel poll of all 32 producer flags (dup x2)
        const u32* fp = flags + (size_t)t * 128 + rg * 32 + (tid & 31);
        for (;;) {
          u32 v = __hip_atomic_load(fp, __ATOMIC_RELAXED, __HIP_MEMORY_SCOPE_AGENT);
          if (__all(v != 0u) || budget == 0u) break;
          --budget;
          __builtin_amdgcn_s_sleep(1);
        }
      }
      __syncthreads();
    }

    // h fragments: plain cache-bypassing wide loads (sc0 sc1 -> read at coherent point)
    const size_t hb = (size_t)(t & 1) * BATCH * HDIM + (size_t)(r0 + lr) * HDIM + w * 128 + lk * 8;
    short8 hH[4], hL[4];
#pragma unroll
    for (int s = 0; s < 4; s++) {
      asm volatile("global_load_dwordx4 %0, %1, off sc0 sc1"
                   : "=&v"(hH[s]) : "v"(Hh + hb + s * 32) : "memory");
      asm volatile("global_load_dwordx4 %0, %1, off sc0 sc1"
                   : "=&v"(hL[s]) : "v"(Hl + hb + s * 32) : "memory");
    }
    asm volatile("s_waitcnt vmcnt(0)" ::: "memory");
    __builtin_amdgcn_sched_barrier(0);

    f32x4 acc[2][2];   // [mat][coltile]
    acc[0][0] = vz; acc[0][1] = vz; acc[1][0] = vz; acc[1][1] = vz;
#pragma unroll
    for (int s = 0; s < 4; s++) {
#pragma unroll
      for (int m = 0; m < 2; m++)
#pragma unroll
        for (int ct = 0; ct < 2; ct++) {
          acc[m][ct] = __builtin_amdgcn_mfma_f32_16x16x32_bf16(hH[s], bwh[m][ct][s], acc[m][ct], 0, 0, 0);
          acc[m][ct] = __builtin_amdgcn_mfma_f32_16x16x32_bf16(hH[s], bwl[m][ct][s], acc[m][ct], 0, 0, 0);
          acc[m][ct] = __builtin_amdgcn_mfma_f32_16x16x32_bf16(hL[s], bwh[m][ct][s], acc[m][ct], 0, 0, 0);
        }
    }

    // scatter partial pre-activations (D: col=l&15, row=(l>>4)*4+r)
#pragma unroll
    for (int m = 0; m < 2; m++)
#pragma unroll
      for (int ct = 0; ct < 2; ct++)
#pragma unroll
        for (int r = 0; r < 4; r++)
          ex[m][w][lk * 4 + r][ct * 16 + lr] = acc[m][ct][r];
    __syncthreads();   // barrier A: partials visible

    float hn0 = 0.f, hn1 = 0.f;
    if (tid < 256) {
      const int ec = cq * 2;
      float cp0 = xc0, cp1 = xc1, ap0 = xa0, ap1 = xa1;
#pragma unroll
      for (int q = 0; q < 8; q++) {
        cp0 += ex[0][q][er][ec];     cp1 += ex[0][q][er][ec + 1];
        ap0 += ex[1][q][er][ec];     ap1 += ex[1][q][er][ec + 1];
      }
      float c0g = fsigm(cp0), c1g = fsigm(cp1);
      float aa0 = 1.f + ftanh(ap0), aa1 = 1.f + ftanh(ap1);
      float th0 = ftanh(xh0 + aa0 * hs0), th1 = ftanh(xh1 + aa1 * hs1);
      hn0 = c0g * hs0 + (1.f - c0g) * th0;
      hn1 = c1g * hs1 + (1.f - c1g) * th1;
      hs0 = hn0; hs1 = hn1;

      // h_{t+1} hi/lo bf16 -> coherent point via agent-scope atomic stores
      u16 hb_0 = f2b(hn0), hb_1 = f2b(hn1);
      u16 lb_0 = f2b(hn0 - bf2f(hb_0)), lb_1 = f2b(hn1 - bf2f(hb_1));
      size_t hidx = ((size_t)((t + 1) & 1) * BATCH * HDIM + (size_t)gr * HDIM + gc) >> 1;
      __hip_atomic_store((u32*)Hh + hidx, (u32)hb_0 | ((u32)hb_1 << 16),
                         __ATOMIC_RELAXED, __HIP_MEMORY_SCOPE_AGENT);
      __hip_atomic_store((u32*)Hl + hidx, (u32)lb_0 | ((u32)lb_1 << 16),
                         __ATOMIC_RELAXED, __HIP_MEMORY_SCOPE_AGENT);
    }

    __syncthreads();   // barrier B: per-wave vmcnt(0) drain -> all h stores ack'd at coherent point
    if (tid == 0)
      __hip_atomic_store(flags + (size_t)(t + 1) * 128 + rg * 32 + cb, 1u,
                         __ATOMIC_RELAXED, __HIP_MEMORY_SCOPE_AGENT);

    // y stores AFTER the release (off the inter-block critical path)
    if (tid < 256) {
      float* yrow = out + (size_t)t * BATCH * HDIM + (size_t)gr * HDIM + gc;
      f32x2 y = {hn0, hn1};
      __builtin_nontemporal_store(y, (f32x2*)yrow);
      if (t == T_STEPS - 1) {
        float* frow = out + (size_t)T_STEPS * BATCH * HDIM + (size_t)gr * HDIM + gc;
        __builtin_nontemporal_store(y, (f32x2*)frow);
      }
    }
  }
}

// ---------------- launcher ----------------
static const size_t SZ_X1 = (size_t)TBm * IDIM * 2;      // 32 MB (hi or lo)
static const size_t SZ_U1 = (size_t)N3 * IDIM * 2;       // 3 MB
static const size_t SZ_W1 = (size_t)2 * HDIM * HDIM * 2; // 4 MB
static const size_t SZ_B  = (size_t)N3 * 4;
static const size_t SZ_H1 = (size_t)2 * BATCH * HDIM * 2;
static const size_t SZ_F  = (size_t)(T_STEPS + 1) * 128 * 4;
static const size_t SZ_TAIL = 2*SZ_X1 + 2*SZ_U1 + 2*SZ_W1 + SZ_B + 2*SZ_H1 + SZ_F;

template<typename PT>
static void launch_path(void* const* d_in, float* out, char* ws, hipStream_t stream) {
  const float* x_seq = (const float*)d_in[0];
  const float* h0   = (const float*)d_in[1];
  const float* U_c  = (const float*)d_in[2];
  const float* W_c  = (const float*)d_in[3];
  const float* b_c  = (const float*)d_in[4];
  const float* U_a  = (const float*)d_in[5];
  const float* W_a  = (const float*)d_in[6];
  const float* b_a  = (const float*)d_in[7];
  const float* U_h  = (const float*)d_in[8];
  const float* b_h  = (const float*)d_in[9];

  const size_t szP = (size_t)TBm * N3 * sizeof(PT);
  PT*  Pb  = (PT*)(ws);
  u16* Xh  = (u16*)(ws + szP);
  u16* Xl  = (u16*)(ws + szP + SZ_X1);
  u16* Uh  = (u16*)(ws + szP + 2*SZ_X1);
  u16* Ul  = (u16*)(ws + szP + 2*SZ_X1 + SZ_U1);
  u16* Wh  = (u16*)(ws + szP + 2*SZ_X1 + 2*SZ_U1);
  u16* Wl  = (u16*)(ws + szP + 2*SZ_X1 + 2*SZ_U1 + SZ_W1);
  float* bias = (float*)(ws + szP + 2*SZ_X1 + 2*SZ_U1 + 2*SZ_W1);
  u16* Hh  = (u16*)((char*)bias + SZ_B);
  u16* Hl  = (u16*)((char*)bias + SZ_B + SZ_H1);
  u32* Fl  = (u32*)((char*)bias + SZ_B + 2*SZ_H1);

  (void)hipMemsetAsync(Fl, 0, SZ_F, stream);
  (void)hipMemcpyAsync(bias + 0 * HDIM, b_c, HDIM * sizeof(float), hipMemcpyDeviceToDevice, stream);
  (void)hipMemcpyAsync(bias + 1 * HDIM, b_a, HDIM * sizeof(float), hipMemcpyDeviceToDevice, stream);
  (void)hipMemcpyAsync(bias + 2 * HDIM, b_h, HDIM * sizeof(float), hipMemcpyDeviceToDevice, stream);

  int n4;
  n4 = TBm * IDIM / 4;
  split_f32<<<(n4 + 255) / 256, 256, 0, stream>>>(x_seq, Xh, Xl, n4);
  n4 = HDIM * IDIM / 4;
  split_f32<<<(n4 + 255) / 256, 256, 0, stream>>>(U_c, Uh + 0 * (size_t)HDIM * IDIM, Ul + 0 * (size_t)HDIM * IDIM, n4);
  split_f32<<<(n4 + 255) / 256, 256, 0, stream>>>(U_a, Uh + 1 * (size_t)HDIM * IDIM, Ul + 1 * (size_t)HDIM * IDIM, n4);
  split_f32<<<(n4 + 255) / 256, 256, 0, stream>>>(U_h, Uh + 2 * (size_t)HDIM * IDIM, Ul + 2 * (size_t)HDIM * IDIM, n4);
  n4 = HDIM * HDIM / 4;
  split_f32<<<(n4 + 255) / 256, 256, 0, stream>>>(W_c, Wh, Wl, n4);
  split_f32<<<(n4 + 255) / 256, 256, 0, stream>>>(W_a, Wh + (size_t)HDIM * HDIM, Wl + (size_t)HDIM * HDIM, n4);
  n4 = BATCH * HDIM / 4;
  split_f32<<<(n4 + 255) / 256, 256, 0, stream>>>(h0, Hh, Hl, n4);

  proj_gemm<PT><<<dim3(TBm / 128, N3 / 128), 256, 0, stream>>>(Xh, Xl, Uh, Ul, bias, Pb);
  scan_kernel<PT><<<NBLK, 512, 0, stream>>>(Pb, Wh, Wl, h0, Hh, Hl, Fl, out);
}

extern "C" void kernel_launch(void* const* d_in, const int* in_sizes, int n_in,
                              void* d_out, int out_size, void* d_ws, size_t ws_size,
                              hipStream_t stream) {
  const size_t need_f32 = (size_t)TBm * N3 * 4 + SZ_TAIL;   // ~463 MB
  const size_t need_f16 = (size_t)TBm * N3 * 2 + SZ_TAIL;   // ~271 MB

  if (ws_size >= need_f32) {
    launch_path<float>(d_in, (float*)d_out, (char*)d_ws, stream);
  } else if (ws_size >= need_f16) {
    launch_path<_Float16>(d_in, (float*)d_out, (char*)d_ws, stream);
  } else {
    float v = 1.0e6f + (float)(ws_size >> 20);   // sentinel: encodes ws MB
    ws_small_kernel<<<2048, 256, 0, stream>>>((float*)d_out, out_size, v);
  }
}

// Round 12
// 2245.656 us; speedup vs baseline: 1.7188x; 1.1443x over previous
//
#include <hip/hip_runtime.h>
#include <stdint.h>

typedef unsigned short u16;
typedef unsigned int u32;
typedef unsigned long long u64;
typedef short short8 __attribute__((ext_vector_type(8)));
typedef float f32x4 __attribute__((ext_vector_type(4)));
typedef float f32x2 __attribute__((ext_vector_type(2)));

#define T_STEPS 512
#define BATCH 64
#define IDIM 512
#define HDIM 1024
#define TBm (T_STEPS*BATCH)      /* 32768 */
#define N3 (3*HDIM)              /* 3072 */
#define NBLK 128                 /* scan blocks: 4 row-groups x 32 col-blocks */
#define PROJ_BLKS (256*24)       /* 6144 proj blocks: bm 0..255 (major), bn 0..23 */

// ---------------- helpers ----------------
__device__ __forceinline__ float bf2f(u16 s) {
  union { u32 u; float f; } v; v.u = ((u32)s) << 16; return v.f;
}
__device__ __forceinline__ u16 f2b(float f) {
  union { float f; u32 u; } v; v.f = f;
  u32 u = v.u;
  u += 0x7fffu + ((u >> 16) & 1u);   // RNE
  return (u16)(u >> 16);
}
__device__ __forceinline__ float ftanh(float x) {
  x = fminf(20.f, fmaxf(-20.f, x));
  float e = __expf(2.f * x);
  return (e - 1.f) / (e + 1.f);
}
__device__ __forceinline__ float fsigm(float x) {
  x = fminf(30.f, fmaxf(-30.f, x));
  return 1.f / (1.f + __expf(-x));
}

// ---------------- f32 -> (bf16 hi, bf16 lo) split, 4 elems/thread ----------------
__global__ void split_f32(const float* __restrict__ src, u16* __restrict__ hi,
                          u16* __restrict__ lo, int n4) {
  int i = blockIdx.x * blockDim.x + threadIdx.x;
  if (i >= n4) return;
  float4 a = ((const float4*)src)[i];
  u16 h0 = f2b(a.x), h1 = f2b(a.y), h2 = f2b(a.z), h3 = f2b(a.w);
  u16 l0 = f2b(a.x - bf2f(h0)), l1 = f2b(a.y - bf2f(h1));
  u16 l2 = f2b(a.z - bf2f(h2)), l3 = f2b(a.w - bf2f(h3));
  uint2 hv; hv.x = (u32)h0 | ((u32)h1 << 16); hv.y = (u32)h2 | ((u32)h3 << 16);
  uint2 lv; lv.x = (u32)l0 | ((u32)l1 << 16); lv.y = (u32)l2 | ((u32)l3 << 16);
  ((uint2*)hi)[i] = hv;
  ((uint2*)lo)[i] = lv;
}

// ---------------- ws-too-small sentinel ----------------
__global__ void ws_small_kernel(float* out, int n, float val) {
  int i = blockIdx.x * blockDim.x + threadIdx.x;
  for (; i < n; i += gridDim.x * blockDim.x) out[i] = val;
}

// ============================ FUSED proj + scan ============================
// Grid = 128 scan blocks (IDs 0..127) + 6144 proj blocks. 512 thr. 96KB static LDS
// -> exactly 1 block/CU -> guaranteed partition: 128 scan CUs + 128 proj CUs.
// PROJ role (IDs >= 128): 128x128 tile of P = Xh@Uh^T + Xh@Ul^T + Xl@Uh^T + bias.
//   bm-major block order so early timesteps' tiles complete first. P stored with
//   sc0/sc1 write-through; vmcnt(0) drain; per-bm counter atomicAdd (24 bn-tiles).
// SCAN role (IDs < 128): round-6 protocol verbatim; gate = h-flags (lanes 0-31)
//   + P-counter==24 (lanes 32-63); P read via bypass loads in the h-load vmcnt batch.
__global__ __launch_bounds__(512, 1) void fused_kernel(
    const u16* __restrict__ Xh, const u16* __restrict__ Xl,
    const u16* __restrict__ Uh, const u16* __restrict__ Ul,
    const u16* __restrict__ Wh, const u16* __restrict__ Wl,
    const float* __restrict__ bias, const float* __restrict__ h0,
    float* __restrict__ Pb, u16* __restrict__ Hh, u16* __restrict__ Hl,
    u32* __restrict__ flags, u32* __restrict__ pcnt, float* __restrict__ out) {
  __shared__ __align__(16) char smem[98304];
  const int tid = threadIdx.x;
  const int w = tid >> 6, l = tid & 63;
  const int lr = l & 15, lk = l >> 4;
  const f32x4 vz = {0.f, 0.f, 0.f, 0.f};

  if (blockIdx.x >= NBLK) {
    // ---------------- proj role ----------------
    const int pid = blockIdx.x - NBLK;
    const int bm = pid / 24, bn = pid % 24;
    u16* Ash = (u16*)smem;
    u16* Asl = Ash + 4096;
    u16* Bsh = Asl + 4096;
    u16* Bsl = Bsh + 4096;
    const int wm = w >> 2, wn = w & 3;      // 2 row-halves x 4 col-quarters
    const int r0t = tid >> 2, kc = tid & 3; // staging: one uint4/thread/array

    const size_t ga = (size_t)(bm * 128 + r0t) * IDIM + kc * 8;
    const size_t gb = (size_t)(bn * 128 + r0t) * IDIM + kc * 8;
    const int la = (kc * 128 + r0t) * 8;

    uint4 rah = *(const uint4*)(Xh + ga);
    uint4 ral = *(const uint4*)(Xl + ga);
    uint4 rbh = *(const uint4*)(Uh + gb);
    uint4 rbl = *(const uint4*)(Ul + gb);

    f32x4 acc[4][2];
#pragma unroll
    for (int i = 0; i < 4; i++) { acc[i][0] = vz; acc[i][1] = vz; }

    for (int kt = 0; kt < 16; kt++) {
      *(uint4*)&Ash[la] = rah;
      *(uint4*)&Asl[la] = ral;
      *(uint4*)&Bsh[la] = rbh;
      *(uint4*)&Bsl[la] = rbl;
      __syncthreads();
      if (kt < 15) {
        size_t ko = (size_t)(kt + 1) * 32;
        rah = *(const uint4*)(Xh + ga + ko);
        ral = *(const uint4*)(Xl + ga + ko);
        rbh = *(const uint4*)(Uh + gb + ko);
        rbl = *(const uint4*)(Ul + gb + ko);
      }
      short8 afh[4], afl[4], bfh[2], bfl[2];
#pragma unroll
      for (int mt = 0; mt < 4; mt++) {
        int idx = (lk * 128 + wm * 64 + mt * 16 + lr) * 8;
        afh[mt] = *(const short8*)&Ash[idx];
        afl[mt] = *(const short8*)&Asl[idx];
      }
#pragma unroll
      for (int nt = 0; nt < 2; nt++) {
        int idx = (lk * 128 + wn * 32 + nt * 16 + lr) * 8;
        bfh[nt] = *(const short8*)&Bsh[idx];
        bfl[nt] = *(const short8*)&Bsl[idx];
      }
#pragma unroll
      for (int mt = 0; mt < 4; mt++)
#pragma unroll
        for (int nt = 0; nt < 2; nt++) {
          acc[mt][nt] = __builtin_amdgcn_mfma_f32_16x16x32_bf16(afh[mt], bfh[nt], acc[mt][nt], 0, 0, 0);
          acc[mt][nt] = __builtin_amdgcn_mfma_f32_16x16x32_bf16(afh[mt], bfl[nt], acc[mt][nt], 0, 0, 0);
          acc[mt][nt] = __builtin_amdgcn_mfma_f32_16x16x32_bf16(afl[mt], bfh[nt], acc[mt][nt], 0, 0, 0);
        }
      __syncthreads();
    }
    // epilogue: write-through P stores (visible at coherent point after vmcnt drain)
#pragma unroll
    for (int mt = 0; mt < 4; mt++)
#pragma unroll
      for (int nt = 0; nt < 2; nt++) {
        int col = bn * 128 + wn * 32 + nt * 16 + lr;
        float bv = bias[col];
#pragma unroll
        for (int r = 0; r < 4; r++) {
          int row = bm * 128 + wm * 64 + mt * 16 + lk * 4 + r;
          float val = acc[mt][nt][r] + bv;
          asm volatile("global_store_dword %0, %1, off sc0 sc1"
                       :: "v"(Pb + (size_t)row * N3 + col), "v"(val) : "memory");
        }
      }
    asm volatile("s_waitcnt vmcnt(0)" ::: "memory");
    __syncthreads();
    if (tid == 0)
      (void)__hip_atomic_fetch_add(pcnt + (size_t)bm * 32, 1u,
                                   __ATOMIC_RELAXED, __HIP_MEMORY_SCOPE_AGENT);
    return;
  }

  // ---------------- scan role (round-6 verbatim + P gating) ----------------
  auto ex = (float (*)[8][16][36])smem;   // [mat][kq][row][col pad36]
  const int blk = blockIdx.x;
  const int cb = blk & 31, rg = blk >> 5;
  const int c0 = cb * 32, r0 = rg * 16;

  // W fragments (plain loads; compiler keeps them in L2 — proven neutral vs pinning)
  short8 bwh[2][2][4], bwl[2][2][4];   // [mat][coltile][ktile]
#pragma unroll
  for (int m = 0; m < 2; m++)
#pragma unroll
    for (int ct = 0; ct < 2; ct++) {
      const size_t woff = ((size_t)m << 20) + (size_t)(c0 + ct * 16 + lr) * HDIM + w * 128 + lk * 8;
#pragma unroll
      for (int s = 0; s < 4; s++) {
        bwh[m][ct][s] = *(const short8*)(Wh + woff + s * 32);
        bwl[m][ct][s] = *(const short8*)(Wl + woff + s * 32);
      }
    }

  const int er = (tid & 255) >> 4;       // 0..15
  const int cq = tid & 15;               // 0..15
  const int gr = r0 + er;
  const int gc = c0 + cq * 2;
  float hs0 = 0.f, hs1 = 0.f;
  if (tid < 256) {
    hs0 = h0[(size_t)gr * HDIM + gc];
    hs1 = h0[(size_t)gr * HDIM + gc + 1];
  }

  u32 budget = 1u << 20;   // poll budget (anti-hang)

#pragma unroll 1
  for (int t = 0; t < T_STEPS; t++) {
    // gate: lanes 0-31 -> h flags (t>0); lanes 32-63 -> P-tile counter for this step
    if (tid < 64) {
      const u32* fp = flags + (size_t)t * 128 + rg * 32 + (l & 31);
      const u32* pc = pcnt + (size_t)(t >> 1) * 32;
      for (;;) {
        u32 v;
        if (l < 32)
          v = (t == 0) ? 1u : __hip_atomic_load(fp, __ATOMIC_RELAXED, __HIP_MEMORY_SCOPE_AGENT);
        else
          v = (__hip_atomic_load(pc, __ATOMIC_RELAXED, __HIP_MEMORY_SCOPE_AGENT) == 24u) ? 1u : 0u;
        if (__all(v != 0u) || budget == 0u) break;
        --budget;
        __builtin_amdgcn_s_sleep(1);
      }
    }
    __syncthreads();

    // P (bypass, joined with h vmcnt batch; consumed only after barrier A)
    f32x2 pc2, pa2, ph2;
    const float* prow = Pb + (size_t)(t * BATCH + gr) * N3 + gc;
    if (tid < 256) {
      asm volatile("global_load_dwordx2 %0, %1, off sc0 sc1" : "=&v"(pc2) : "v"(prow) : "memory");
      asm volatile("global_load_dwordx2 %0, %1, off sc0 sc1" : "=&v"(pa2) : "v"(prow + HDIM) : "memory");
      asm volatile("global_load_dwordx2 %0, %1, off sc0 sc1" : "=&v"(ph2) : "v"(prow + 2 * HDIM) : "memory");
    }

    // h fragments: cache-bypassing wide loads (read at coherent point)
    const size_t hb = (size_t)(t & 1) * BATCH * HDIM + (size_t)(r0 + lr) * HDIM + w * 128 + lk * 8;
    short8 hH[4], hL[4];
#pragma unroll
    for (int s = 0; s < 4; s++) {
      asm volatile("global_load_dwordx4 %0, %1, off sc0 sc1"
                   : "=&v"(hH[s]) : "v"(Hh + hb + s * 32) : "memory");
      asm volatile("global_load_dwordx4 %0, %1, off sc0 sc1"
                   : "=&v"(hL[s]) : "v"(Hl + hb + s * 32) : "memory");
    }
    asm volatile("s_waitcnt vmcnt(0)" ::: "memory");
    __builtin_amdgcn_sched_barrier(0);

    f32x4 acc[2][2];   // [mat][coltile]
    acc[0][0] = vz; acc[0][1] = vz; acc[1][0] = vz; acc[1][1] = vz;
#pragma unroll
    for (int s = 0; s < 4; s++) {
#pragma unroll
      for (int m = 0; m < 2; m++)
#pragma unroll
        for (int ct = 0; ct < 2; ct++) {
          acc[m][ct] = __builtin_amdgcn_mfma_f32_16x16x32_bf16(hH[s], bwh[m][ct][s], acc[m][ct], 0, 0, 0);
          acc[m][ct] = __builtin_amdgcn_mfma_f32_16x16x32_bf16(hH[s], bwl[m][ct][s], acc[m][ct], 0, 0, 0);
          acc[m][ct] = __builtin_amdgcn_mfma_f32_16x16x32_bf16(hL[s], bwh[m][ct][s], acc[m][ct], 0, 0, 0);
        }
    }

    // scatter partial pre-activations (D: col=l&15, row=(l>>4)*4+r)
#pragma unroll
    for (int m = 0; m < 2; m++)
#pragma unroll
      for (int ct = 0; ct < 2; ct++)
#pragma unroll
        for (int r = 0; r < 4; r++)
          ex[m][w][lk * 4 + r][ct * 16 + lr] = acc[m][ct][r];
    __syncthreads();   // barrier A: partials visible

    float hn0 = 0.f, hn1 = 0.f;
    if (tid < 256) {
      const int ec = cq * 2;
      float cp0 = pc2[0], cp1 = pc2[1], ap0 = pa2[0], ap1 = pa2[1];
#pragma unroll
      for (int q = 0; q < 8; q++) {
        cp0 += ex[0][q][er][ec];     cp1 += ex[0][q][er][ec + 1];
        ap0 += ex[1][q][er][ec];     ap1 += ex[1][q][er][ec + 1];
      }
      float c0g = fsigm(cp0), c1g = fsigm(cp1);
      float aa0 = 1.f + ftanh(ap0), aa1 = 1.f + ftanh(ap1);
      float th0 = ftanh(ph2[0] + aa0 * hs0), th1 = ftanh(ph2[1] + aa1 * hs1);
      hn0 = c0g * hs0 + (1.f - c0g) * th0;
      hn1 = c1g * hs1 + (1.f - c1g) * th1;
      hs0 = hn0; hs1 = hn1;

      // h_{t+1} hi/lo bf16 -> coherent point via agent-scope atomic stores
      u16 hb_0 = f2b(hn0), hb_1 = f2b(hn1);
      u16 lb_0 = f2b(hn0 - bf2f(hb_0)), lb_1 = f2b(hn1 - bf2f(hb_1));
      size_t hidx = ((size_t)((t + 1) & 1) * BATCH * HDIM + (size_t)gr * HDIM + gc) >> 1;
      __hip_atomic_store((u32*)Hh + hidx, (u32)hb_0 | ((u32)hb_1 << 16),
                         __ATOMIC_RELAXED, __HIP_MEMORY_SCOPE_AGENT);
      __hip_atomic_store((u32*)Hl + hidx, (u32)lb_0 | ((u32)lb_1 << 16),
                         __ATOMIC_RELAXED, __HIP_MEMORY_SCOPE_AGENT);
    }

    __syncthreads();   // barrier B: per-wave vmcnt(0) drain -> h stores ack'd
    if (tid == 0)
      __hip_atomic_store(flags + (size_t)(t + 1) * 128 + rg * 32 + cb, 1u,
                         __ATOMIC_RELAXED, __HIP_MEMORY_SCOPE_AGENT);

    // y stores AFTER the release (off the inter-block critical path)
    if (tid < 256) {
      float* yrow = out + (size_t)t * BATCH * HDIM + (size_t)gr * HDIM + gc;
      f32x2 y = {hn0, hn1};
      __builtin_nontemporal_store(y, (f32x2*)yrow);
      if (t == T_STEPS - 1) {
        float* frow = out + (size_t)T_STEPS * BATCH * HDIM + (size_t)gr * HDIM + gc;
        __builtin_nontemporal_store(y, (f32x2*)frow);
      }
    }
  }
}

// ---------------- launcher ----------------
static const size_t SZ_P  = (size_t)TBm * N3 * 4;        // 402.7 MB f32 P
static const size_t SZ_X1 = (size_t)TBm * IDIM * 2;      // 33.6 MB (hi or lo)
static const size_t SZ_U1 = (size_t)N3 * IDIM * 2;       // 3.1 MB
static const size_t SZ_W1 = (size_t)2 * HDIM * HDIM * 2; // 4.2 MB
static const size_t SZ_B  = (size_t)N3 * 4;
static const size_t SZ_H1 = (size_t)2 * BATCH * HDIM * 2;
static const size_t SZ_F  = (size_t)(T_STEPS + 1) * 128 * 4;
static const size_t SZ_PC = (size_t)256 * 32 * 4;        // per-bm P counters (line-padded)
static const size_t WS_NEED = SZ_P + 2*SZ_X1 + 2*SZ_U1 + 2*SZ_W1 + SZ_B + 2*SZ_H1 + SZ_F + SZ_PC;

extern "C" void kernel_launch(void* const* d_in, const int* in_sizes, int n_in,
                              void* d_out, int out_size, void* d_ws, size_t ws_size,
                              hipStream_t stream) {
  const float* x_seq = (const float*)d_in[0];
  const float* h0   = (const float*)d_in[1];
  const float* U_c  = (const float*)d_in[2];
  const float* W_c  = (const float*)d_in[3];
  const float* b_c  = (const float*)d_in[4];
  const float* U_a  = (const float*)d_in[5];
  const float* W_a  = (const float*)d_in[6];
  const float* b_a  = (const float*)d_in[7];
  const float* U_h  = (const float*)d_in[8];
  const float* b_h  = (const float*)d_in[9];

  if (ws_size < WS_NEED) {
    float v = 1.0e6f + (float)(ws_size >> 20);   // sentinel: encodes ws MB
    ws_small_kernel<<<2048, 256, 0, stream>>>((float*)d_out, out_size, v);
    return;
  }

  char* ws = (char*)d_ws;
  float* Pb = (float*)(ws);
  u16* Xh  = (u16*)(ws + SZ_P);
  u16* Xl  = (u16*)(ws + SZ_P + SZ_X1);
  u16* Uh  = (u16*)(ws + SZ_P + 2*SZ_X1);
  u16* Ul  = (u16*)(ws + SZ_P + 2*SZ_X1 + SZ_U1);
  u16* Wh  = (u16*)(ws + SZ_P + 2*SZ_X1 + 2*SZ_U1);
  u16* Wl  = (u16*)(ws + SZ_P + 2*SZ_X1 + 2*SZ_U1 + SZ_W1);
  float* bias = (float*)(ws + SZ_P + 2*SZ_X1 + 2*SZ_U1 + 2*SZ_W1);
  u16* Hh  = (u16*)((char*)bias + SZ_B);
  u16* Hl  = (u16*)((char*)bias + SZ_B + SZ_H1);
  u32* Fl  = (u32*)((char*)bias + SZ_B + 2*SZ_H1);
  u32* Pc  = (u32*)((char*)bias + SZ_B + 2*SZ_H1 + SZ_F);

  (void)hipMemsetAsync(Fl, 0, SZ_F + SZ_PC, stream);   // flags + pcnt (contiguous)
  (void)hipMemcpyAsync(bias + 0 * HDIM, b_c, HDIM * sizeof(float), hipMemcpyDeviceToDevice, stream);
  (void)hipMemcpyAsync(bias + 1 * HDIM, b_a, HDIM * sizeof(float), hipMemcpyDeviceToDevice, stream);
  (void)hipMemcpyAsync(bias + 2 * HDIM, b_h, HDIM * sizeof(float), hipMemcpyDeviceToDevice, stream);

  int n4;
  n4 = TBm * IDIM / 4;
  split_f32<<<(n4 + 255) / 256, 256, 0, stream>>>(x_seq, Xh, Xl, n4);
  n4 = HDIM * IDIM / 4;
  split_f32<<<(n4 + 255) / 256, 256, 0, stream>>>(U_c, Uh + 0 * (size_t)HDIM * IDIM, Ul + 0 * (size_t)HDIM * IDIM, n4);
  split_f32<<<(n4 + 255) / 256, 256, 0, stream>>>(U_a, Uh + 1 * (size_t)HDIM * IDIM, Ul + 1 * (size_t)HDIM * IDIM, n4);
  split_f32<<<(n4 + 255) / 256, 256, 0, stream>>>(U_h, Uh + 2 * (size_t)HDIM * IDIM, Ul + 2 * (size_t)HDIM * IDIM, n4);
  n4 = HDIM * HDIM / 4;
  split_f32<<<(n4 + 255) / 256, 256, 0, stream>>>(W_c, Wh, Wl, n4);
  split_f32<<<(n4 + 255) / 256, 256, 0, stream>>>(W_a, Wh + (size_t)HDIM * HDIM, Wl + (size_t)HDIM * HDIM, n4);
  n4 = BATCH * HDIM / 4;
  split_f32<<<(n4 + 255) / 256, 256, 0, stream>>>(h0, Hh, Hl, n4);

  fused_kernel<<<NBLK + PROJ_BLKS, 512, 0, stream>>>(Xh, Xl, Uh, Ul, Wh, Wl, bias, h0,
                                                     Pb, Hh, Hl, Fl, Pc, (float*)d_out);
}

// Round 16
// 2239.517 us; speedup vs baseline: 1.7235x; 1.0027x over previous
//
#include <hip/hip_runtime.h>
#include <stdint.h>

typedef unsigned short u16;
typedef unsigned int u32;
typedef unsigned long long u64;
typedef short short8 __attribute__((ext_vector_type(8)));
typedef float f32x4 __attribute__((ext_vector_type(4)));
typedef float f32x2 __attribute__((ext_vector_type(2)));

#define T_STEPS 512
#define BATCH 64
#define IDIM 512
#define HDIM 1024
#define TBm (T_STEPS*BATCH)      /* 32768 */
#define N3 (3*HDIM)              /* 3072 */
#define NBLK 128                 /* scan blocks: 4 row-groups x 32 col-blocks */
#define PROJ_BLKS (256*24)       /* 6144 proj blocks: bm 0..255 (major), bn 0..23 */

// ---------------- workspace layout ----------------
static const size_t SZ_P  = (size_t)TBm * N3 * 4;        // 402.7 MB f32 P
static const size_t SZ_X1 = (size_t)TBm * IDIM * 2;      // 33.6 MB (hi or lo)
static const size_t SZ_U1 = (size_t)N3 * IDIM * 2;       // 3.1 MB
static const size_t SZ_W1 = (size_t)2 * HDIM * HDIM * 2; // 4.2 MB
static const size_t SZ_B  = (size_t)N3 * 4;
static const size_t SZ_H1 = (size_t)2 * BATCH * HDIM * 2;
static const size_t SZ_F  = (size_t)(T_STEPS + 1) * 128 * 4;  // flags
static const size_t SZ_PC = (size_t)256 * 32 * 4;        // per-bm P counters
static const size_t WS_NEED = SZ_P + 2*SZ_X1 + 2*SZ_U1 + 2*SZ_W1 + SZ_B + 2*SZ_H1 + SZ_F + SZ_PC;

// ---------------- helpers ----------------
__device__ __forceinline__ float bf2f(u16 s) {
  union { u32 u; float f; } v; v.u = ((u32)s) << 16; return v.f;
}
__device__ __forceinline__ u16 f2b(float f) {
  union { float f; u32 u; } v; v.f = f;
  u32 u = v.u;
  u += 0x7fffu + ((u >> 16) & 1u);   // RNE
  return (u16)(u >> 16);
}
__device__ __forceinline__ float ftanh(float x) {
  x = fminf(20.f, fmaxf(-20.f, x));
  float e = __expf(2.f * x);
  return (e - 1.f) / (e + 1.f);
}
__device__ __forceinline__ float fsigm(float x) {
  x = fminf(30.f, fmaxf(-30.f, x));
  return 1.f / (1.f + __expf(-x));
}
__device__ __forceinline__ void split4(const float* __restrict__ s, u16* __restrict__ hi,
                                       u16* __restrict__ lo, int i) {
  float4 a = ((const float4*)s)[i];
  u16 h0 = f2b(a.x), h1 = f2b(a.y), h2 = f2b(a.z), h3 = f2b(a.w);
  u16 l0 = f2b(a.x - bf2f(h0)), l1 = f2b(a.y - bf2f(h1));
  u16 l2 = f2b(a.z - bf2f(h2)), l3 = f2b(a.w - bf2f(h3));
  uint2 hv; hv.x = (u32)h0 | ((u32)h1 << 16); hv.y = (u32)h2 | ((u32)h3 << 16);
  uint2 lv; lv.x = (u32)l0 | ((u32)l1 << 16); lv.y = (u32)l2 | ((u32)l3 << 16);
  ((uint2*)hi)[i] = hv;
  ((uint2*)lo)[i] = lv;
}

// ---------------- merged prologue: all splits + bias copy, ONE launch ----------------
// (flags/pcnt zeroing deliberately NOT here: plain kernel stores to sync state are not
//  reliably IC-visible under graph replay — r15 post-timing divergence. hipMemsetAsync
//  (DMA path, r12-proven across replays) handles them.)
#define NX (TBm*IDIM/4)        /* 4194304 */
#define NU (HDIM*IDIM/4)       /* 131072  */
#define NW (HDIM*HDIM/4)       /* 262144  */
#define NH (BATCH*HDIM/4)      /* 16384   */
#define NBIAS (HDIM/4)         /* 256 per bias vector */
#define USLOT (HDIM*IDIM)      /* u16 elems per U matrix */
#define WSLOT (HDIM*HDIM)
__global__ void prologue(const float* __restrict__ x_seq, const float* __restrict__ U_c,
                         const float* __restrict__ U_a, const float* __restrict__ U_h,
                         const float* __restrict__ W_c, const float* __restrict__ W_a,
                         const float* __restrict__ h0,
                         const float* __restrict__ b_c, const float* __restrict__ b_a,
                         const float* __restrict__ b_h,
                         u16* __restrict__ Xh, u16* __restrict__ Xl,
                         u16* __restrict__ Uh, u16* __restrict__ Ul,
                         u16* __restrict__ Wh, u16* __restrict__ Wl,
                         u16* __restrict__ Hh, u16* __restrict__ Hl,
                         float* __restrict__ bias) {
  const int total = NX + 3*NU + 2*NW + NH + 3*NBIAS;
  for (int i = blockIdx.x * blockDim.x + threadIdx.x; i < total; i += gridDim.x * blockDim.x) {
    int j = i;
    if (j < NX) { split4(x_seq, Xh, Xl, j); continue; }              j -= NX;
    if (j < NU) { split4(U_c, Uh,           Ul,           j); continue; } j -= NU;
    if (j < NU) { split4(U_a, Uh + USLOT,   Ul + USLOT,   j); continue; } j -= NU;
    if (j < NU) { split4(U_h, Uh + 2*USLOT, Ul + 2*USLOT, j); continue; } j -= NU;
    if (j < NW) { split4(W_c, Wh,           Wl,           j); continue; } j -= NW;
    if (j < NW) { split4(W_a, Wh + WSLOT,   Wl + WSLOT,   j); continue; } j -= NW;
    if (j < NH) { split4(h0, Hh, Hl, j); continue; }                 j -= NH;
    if (j < NBIAS) { ((float4*)bias)[j] = ((const float4*)b_c)[j]; continue; } j -= NBIAS;
    if (j < NBIAS) { ((float4*)(bias + HDIM))[j] = ((const float4*)b_a)[j]; continue; } j -= NBIAS;
    ((float4*)(bias + 2*HDIM))[j] = ((const float4*)b_h)[j];
  }
}

// ---------------- ws-too-small sentinel ----------------
__global__ void ws_small_kernel(float* out, int n, float val) {
  int i = blockIdx.x * blockDim.x + threadIdx.x;
  for (; i < n; i += gridDim.x * blockDim.x) out[i] = val;
}

// ============================ FUSED proj + scan (r12, byte-identical) ============================
// Grid = 128 scan blocks (IDs 0..127) + 6144 proj blocks. 512 thr. 96KB static LDS
// -> exactly 1 block/CU -> guaranteed partition: 128 scan CUs + 128 proj CUs.
__global__ __launch_bounds__(512, 1) void fused_kernel(
    const u16* __restrict__ Xh, const u16* __restrict__ Xl,
    const u16* __restrict__ Uh, const u16* __restrict__ Ul,
    const u16* __restrict__ Wh, const u16* __restrict__ Wl,
    const float* __restrict__ bias, const float* __restrict__ h0,
    float* __restrict__ Pb, u16* __restrict__ Hh, u16* __restrict__ Hl,
    u32* __restrict__ flags, u32* __restrict__ pcnt, float* __restrict__ out) {
  __shared__ __align__(16) char smem[98304];
  const int tid = threadIdx.x;
  const int w = tid >> 6, l = tid & 63;
  const int lr = l & 15, lk = l >> 4;
  const f32x4 vz = {0.f, 0.f, 0.f, 0.f};

  if (blockIdx.x >= NBLK) {
    // ---------------- proj role ----------------
    const int pid = blockIdx.x - NBLK;
    const int bm = pid / 24, bn = pid % 24;
    u16* Ash = (u16*)smem;
    u16* Asl = Ash + 4096;
    u16* Bsh = Asl + 4096;
    u16* Bsl = Bsh + 4096;
    const int wm = w >> 2, wn = w & 3;      // 2 row-halves x 4 col-quarters
    const int r0t = tid >> 2, kc = tid & 3; // staging: one uint4/thread/array

    const size_t ga = (size_t)(bm * 128 + r0t) * IDIM + kc * 8;
    const size_t gb = (size_t)(bn * 128 + r0t) * IDIM + kc * 8;
    const int la = (kc * 128 + r0t) * 8;

    uint4 rah = *(const uint4*)(Xh + ga);
    uint4 ral = *(const uint4*)(Xl + ga);
    uint4 rbh = *(const uint4*)(Uh + gb);
    uint4 rbl = *(const uint4*)(Ul + gb);

    f32x4 acc[4][2];
#pragma unroll
    for (int i = 0; i < 4; i++) { acc[i][0] = vz; acc[i][1] = vz; }

    for (int kt = 0; kt < 16; kt++) {
      *(uint4*)&Ash[la] = rah;
      *(uint4*)&Asl[la] = ral;
      *(uint4*)&Bsh[la] = rbh;
      *(uint4*)&Bsl[la] = rbl;
      __syncthreads();
      if (kt < 15) {
        size_t ko = (size_t)(kt + 1) * 32;
        rah = *(const uint4*)(Xh + ga + ko);
        ral = *(const uint4*)(Xl + ga + ko);
        rbh = *(const uint4*)(Uh + gb + ko);
        rbl = *(const uint4*)(Ul + gb + ko);
      }
      short8 afh[4], afl[4], bfh[2], bfl[2];
#pragma unroll
      for (int mt = 0; mt < 4; mt++) {
        int idx = (lk * 128 + wm * 64 + mt * 16 + lr) * 8;
        afh[mt] = *(const short8*)&Ash[idx];
        afl[mt] = *(const short8*)&Asl[idx];
      }
#pragma unroll
      for (int nt = 0; nt < 2; nt++) {
        int idx = (lk * 128 + wn * 32 + nt * 16 + lr) * 8;
        bfh[nt] = *(const short8*)&Bsh[idx];
        bfl[nt] = *(const short8*)&Bsl[idx];
      }
#pragma unroll
      for (int mt = 0; mt < 4; mt++)
#pragma unroll
        for (int nt = 0; nt < 2; nt++) {
          acc[mt][nt] = __builtin_amdgcn_mfma_f32_16x16x32_bf16(afh[mt], bfh[nt], acc[mt][nt], 0, 0, 0);
          acc[mt][nt] = __builtin_amdgcn_mfma_f32_16x16x32_bf16(afh[mt], bfl[nt], acc[mt][nt], 0, 0, 0);
          acc[mt][nt] = __builtin_amdgcn_mfma_f32_16x16x32_bf16(afl[mt], bfh[nt], acc[mt][nt], 0, 0, 0);
        }
      __syncthreads();
    }
    // epilogue: write-through P stores (visible at coherent point after vmcnt drain)
#pragma unroll
    for (int mt = 0; mt < 4; mt++)
#pragma unroll
      for (int nt = 0; nt < 2; nt++) {
        int col = bn * 128 + wn * 32 + nt * 16 + lr;
        float bv = bias[col];
#pragma unroll
        for (int r = 0; r < 4; r++) {
          int row = bm * 128 + wm * 64 + mt * 16 + lk * 4 + r;
          float val = acc[mt][nt][r] + bv;
          asm volatile("global_store_dword %0, %1, off sc0 sc1"
                       :: "v"(Pb + (size_t)row * N3 + col), "v"(val) : "memory");
        }
      }
    asm volatile("s_waitcnt vmcnt(0)" ::: "memory");
    __syncthreads();
    if (tid == 0)
      (void)__hip_atomic_fetch_add(pcnt + (size_t)bm * 32, 1u,
                                   __ATOMIC_RELAXED, __HIP_MEMORY_SCOPE_AGENT);
    return;
  }

  // ---------------- scan role (round-6 protocol + P gating) ----------------
  auto ex = (float (*)[8][16][36])smem;   // [mat][kq][row][col pad36]
  const int blk = blockIdx.x;
  const int cb = blk & 31, rg = blk >> 5;
  const int c0 = cb * 32, r0 = rg * 16;

  // W fragments (plain loads; L2-resident — pinning proven neutral r10/r11)
  short8 bwh[2][2][4], bwl[2][2][4];   // [mat][coltile][ktile]
#pragma unroll
  for (int m = 0; m < 2; m++)
#pragma unroll
    for (int ct = 0; ct < 2; ct++) {
      const size_t woff = ((size_t)m << 20) + (size_t)(c0 + ct * 16 + lr) * HDIM + w * 128 + lk * 8;
#pragma unroll
      for (int s = 0; s < 4; s++) {
        bwh[m][ct][s] = *(const short8*)(Wh + woff + s * 32);
        bwl[m][ct][s] = *(const short8*)(Wl + woff + s * 32);
      }
    }

  const int er = (tid & 255) >> 4;       // 0..15
  const int cq = tid & 15;               // 0..15
  const int gr = r0 + er;
  const int gc = c0 + cq * 2;
  float hs0 = 0.f, hs1 = 0.f;
  if (tid < 256) {
    hs0 = h0[(size_t)gr * HDIM + gc];
    hs1 = h0[(size_t)gr * HDIM + gc + 1];
  }

  u32 budget = 1u << 20;   // poll budget (anti-hang)

#pragma unroll 1
  for (int t = 0; t < T_STEPS; t++) {
    // gate: lanes 0-31 -> h flags (t>0); lanes 32-63 -> P-tile counter for this step
    if (tid < 64) {
      const u32* fp = flags + (size_t)t * 128 + rg * 32 + (l & 31);
      const u32* pc = pcnt + (size_t)(t >> 1) * 32;
      for (;;) {
        u32 v;
        if (l < 32)
          v = (t == 0) ? 1u : __hip_atomic_load(fp, __ATOMIC_RELAXED, __HIP_MEMORY_SCOPE_AGENT);
        else
          v = (__hip_atomic_load(pc, __ATOMIC_RELAXED, __HIP_MEMORY_SCOPE_AGENT) == 24u) ? 1u : 0u;
        if (__all(v != 0u) || budget == 0u) break;
        --budget;
        __builtin_amdgcn_s_sleep(1);
      }
    }
    __syncthreads();

    // P (bypass, joined with h vmcnt batch; consumed only after barrier A)
    f32x2 pc2, pa2, ph2;
    const float* prow = Pb + (size_t)(t * BATCH + gr) * N3 + gc;
    if (tid < 256) {
      asm volatile("global_load_dwordx2 %0, %1, off sc0 sc1" : "=&v"(pc2) : "v"(prow) : "memory");
      asm volatile("global_load_dwordx2 %0, %1, off sc0 sc1" : "=&v"(pa2) : "v"(prow + HDIM) : "memory");
      asm volatile("global_load_dwordx2 %0, %1, off sc0 sc1" : "=&v"(ph2) : "v"(prow + 2 * HDIM) : "memory");
    }

    // h fragments: cache-bypassing wide loads (read at coherent point)
    const size_t hb = (size_t)(t & 1) * BATCH * HDIM + (size_t)(r0 + lr) * HDIM + w * 128 + lk * 8;
    short8 hH[4], hL[4];
#pragma unroll
    for (int s = 0; s < 4; s++) {
      asm volatile("global_load_dwordx4 %0, %1, off sc0 sc1"
                   : "=&v"(hH[s]) : "v"(Hh + hb + s * 32) : "memory");
      asm volatile("global_load_dwordx4 %0, %1, off sc0 sc1"
                   : "=&v"(hL[s]) : "v"(Hl + hb + s * 32) : "memory");
    }
    asm volatile("s_waitcnt vmcnt(0)" ::: "memory");
    __builtin_amdgcn_sched_barrier(0);

    f32x4 acc[2][2];   // [mat][coltile]
    acc[0][0] = vz; acc[0][1] = vz; acc[1][0] = vz; acc[1][1] = vz;
#pragma unroll
    for (int s = 0; s < 4; s++) {
#pragma unroll
      for (int m = 0; m < 2; m++)
#pragma unroll
        for (int ct = 0; ct < 2; ct++) {
          acc[m][ct] = __builtin_amdgcn_mfma_f32_16x16x32_bf16(hH[s], bwh[m][ct][s], acc[m][ct], 0, 0, 0);
          acc[m][ct] = __builtin_amdgcn_mfma_f32_16x16x32_bf16(hH[s], bwl[m][ct][s], acc[m][ct], 0, 0, 0);
          acc[m][ct] = __builtin_amdgcn_mfma_f32_16x16x32_bf16(hL[s], bwh[m][ct][s], acc[m][ct], 0, 0, 0);
        }
    }

    // scatter partial pre-activations (D: col=l&15, row=(l>>4)*4+r)
#pragma unroll
    for (int m = 0; m < 2; m++)
#pragma unroll
      for (int ct = 0; ct < 2; ct++)
#pragma unroll
        for (int r = 0; r < 4; r++)
          ex[m][w][lk * 4 + r][ct * 16 + lr] = acc[m][ct][r];
    __syncthreads();   // barrier A: partials visible

    float hn0 = 0.f, hn1 = 0.f;
    if (tid < 256) {
      const int ec = cq * 2;
      float cp0 = pc2[0], cp1 = pc2[1], ap0 = pa2[0], ap1 = pa2[1];
#pragma unroll
      for (int q = 0; q < 8; q++) {
        cp0 += ex[0][q][er][ec];     cp1 += ex[0][q][er][ec + 1];
        ap0 += ex[1][q][er][ec];     ap1 += ex[1][q][er][ec + 1];
      }
      float c0g = fsigm(cp0), c1g = fsigm(cp1);
      float aa0 = 1.f + ftanh(ap0), aa1 = 1.f + ftanh(ap1);
      float th0 = ftanh(ph2[0] + aa0 * hs0), th1 = ftanh(ph2[1] + aa1 * hs1);
      hn0 = c0g * hs0 + (1.f - c0g) * th0;
      hn1 = c1g * hs1 + (1.f - c1g) * th1;
      hs0 = hn0; hs1 = hn1;

      // h_{t+1} hi/lo bf16 -> coherent point via agent-scope atomic stores
      u16 hb_0 = f2b(hn0), hb_1 = f2b(hn1);
      u16 lb_0 = f2b(hn0 - bf2f(hb_0)), lb_1 = f2b(hn1 - bf2f(hb_1));
      size_t hidx = ((size_t)((t + 1) & 1) * BATCH * HDIM + (size_t)gr * HDIM + gc) >> 1;
      __hip_atomic_store((u32*)Hh + hidx, (u32)hb_0 | ((u32)hb_1 << 16),
                         __ATOMIC_RELAXED, __HIP_MEMORY_SCOPE_AGENT);
      __hip_atomic_store((u32*)Hl + hidx, (u32)lb_0 | ((u32)lb_1 << 16),
                         __ATOMIC_RELAXED, __HIP_MEMORY_SCOPE_AGENT);
    }

    __syncthreads();   // barrier B: per-wave vmcnt(0) drain -> h stores ack'd
    if (tid == 0)
      __hip_atomic_store(flags + (size_t)(t + 1) * 128 + rg * 32 + cb, 1u,
                         __ATOMIC_RELAXED, __HIP_MEMORY_SCOPE_AGENT);

    // y stores AFTER the release (off the inter-block critical path)
    if (tid < 256) {
      float* yrow = out + (size_t)t * BATCH * HDIM + (size_t)gr * HDIM + gc;
      f32x2 y = {hn0, hn1};
      __builtin_nontemporal_store(y, (f32x2*)yrow);
      if (t == T_STEPS - 1) {
        float* frow = out + (size_t)T_STEPS * BATCH * HDIM + (size_t)gr * HDIM + gc;
        __builtin_nontemporal_store(y, (f32x2*)frow);
      }
    }
  }
}

// ---------------- launcher ----------------
extern "C" void kernel_launch(void* const* d_in, const int* in_sizes, int n_in,
                              void* d_out, int out_size, void* d_ws, size_t ws_size,
                              hipStream_t stream) {
  const float* x_seq = (const float*)d_in[0];
  const float* h0   = (const float*)d_in[1];
  const float* U_c  = (const float*)d_in[2];
  const float* W_c  = (const float*)d_in[3];
  const float* b_c  = (const float*)d_in[4];
  const float* U_a  = (const float*)d_in[5];
  const float* W_a  = (const float*)d_in[6];
  const float* b_a  = (const float*)d_in[7];
  const float* U_h  = (const float*)d_in[8];
  const float* b_h  = (const float*)d_in[9];

  if (ws_size < WS_NEED) {
    float v = 1.0e6f + (float)(ws_size >> 20);   // sentinel: encodes ws MB
    ws_small_kernel<<<2048, 256, 0, stream>>>((float*)d_out, out_size, v);
    return;
  }

  char* ws = (char*)d_ws;
  float* Pb = (float*)(ws);
  u16* Xh  = (u16*)(ws + SZ_P);
  u16* Xl  = (u16*)(ws + SZ_P + SZ_X1);
  u16* Uh  = (u16*)(ws + SZ_P + 2*SZ_X1);
  u16* Ul  = (u16*)(ws + SZ_P + 2*SZ_X1 + SZ_U1);
  u16* Wh  = (u16*)(ws + SZ_P + 2*SZ_X1 + 2*SZ_U1);
  u16* Wl  = (u16*)(ws + SZ_P + 2*SZ_X1 + 2*SZ_U1 + SZ_W1);
  float* bias = (float*)(ws + SZ_P + 2*SZ_X1 + 2*SZ_U1 + 2*SZ_W1);
  u16* Hh  = (u16*)((char*)bias + SZ_B);
  u16* Hl  = (u16*)((char*)bias + SZ_B + SZ_H1);
  u32* Fl  = (u32*)((char*)bias + SZ_B + 2*SZ_H1);
  u32* Pc  = (u32*)((char*)bias + SZ_B + 2*SZ_H1 + SZ_F);

  // sync state (flags+pcnt) zeroed via DMA memset — IC-coherent, replay-safe (r12-proven).
  (void)hipMemsetAsync(Fl, 0, SZ_F + SZ_PC, stream);

  prologue<<<4096, 256, 0, stream>>>(x_seq, U_c, U_a, U_h, W_c, W_a, h0, b_c, b_a, b_h,
                                     Xh, Xl, Uh, Ul, Wh, Wl, Hh, Hl, bias);

  fused_kernel<<<NBLK + PROJ_BLKS, 512, 0, stream>>>(Xh, Xl, Uh, Ul, Wh, Wl, bias, h0,
                                                     Pb, Hh, Hl, Fl, Pc, (float*)d_out);
}